// Round 3
// baseline (521.732 us; speedup 1.0000x reference)
//
#include <hip/hip_runtime.h>
#include <stdint.h>

// ---------------------------------------------------------------------------
// Round 14: port the r13 8-wave restructure to k1. Changes vs r13:
//   - k1: 512 threads / 8 waves per block; each wave owns a 64x16 output
//     slice (nt dimension eliminated). Halves per-wave accumulator state
//     (breg[4][2]->[4], ag/al_ [4][2]->[4]) so true pressure fits the
//     128-reg unified (VGPR+AGPR) bin spill-free at 2 blocks/CU.
//     Weight traffic per block unchanged (wave w = column-block cb=w).
//     LN uses the 512-thread helpers (same as k2 since r13). Per-output
//     kk-ascending 6-MFMA order and sm-merge pairing breg[mt]+breg[mt+2]
//     preserved.
//   - k2, reductions, pack: r13 verbatim.
// ---------------------------------------------------------------------------

typedef __attribute__((ext_vector_type(8))) short          s16x8;
typedef __attribute__((ext_vector_type(8))) unsigned short u16x8;
typedef __attribute__((ext_vector_type(4))) float          f32x4;

#define MFMAB(A, B, C) __builtin_amdgcn_mfma_f32_16x16x32_bf16((A), (B), (C), 0, 0, 0)

__device__ __forceinline__ unsigned short f2b(float x) {   // f32 -> bf16 RNE
  uint32_t u = __builtin_bit_cast(uint32_t, x);
  uint32_t r = (u + 0x7FFFu + ((u >> 16) & 1u)) >> 16;
  return (unsigned short)r;
}
__device__ __forceinline__ float b2f(unsigned short u) {
  return __builtin_bit_cast(float, (uint32_t)u << 16);
}
__device__ __forceinline__ float sigm(float x) { return 1.0f / (1.0f + __expf(-x)); }

#define LOADB(dst, ptr) s16x8 dst = __builtin_bit_cast(s16x8, *(const u16x8*)(ptr))

#define ZL_STRIDE 132   // floats per LDS row (16B-aligned rows)

// shared arena (38400 B): zl f32[64][132] @0; Ah @0 (aliases), Al @16384;
// red @33792 (512 thr * 2 f = 4096 B), stats @37888 (512 B).
#define ARENA_BYTES 38400
#define RED_OFF     33792
#define STATS_OFF   37888

// ---------------- weight pack: fragment-ordered -----------------------------
// hi: wP[mat*16384 + cb*2048 + kk*512 + l*8 + e]; lo at +98304.
// value = src[(kk*32 + (l>>4)*8 + e)*128 + cb*16 + (l&15)]
// mats: 0=ga 1=a 2=gb 3=b 4=go 5=o
__global__ void k_pack(const float* __restrict__ wga, const float* __restrict__ wa,
                       const float* __restrict__ wgb, const float* __restrict__ wb,
                       const float* __restrict__ wgo, const float* __restrict__ wo,
                       unsigned short* __restrict__ wP) {
  int gid = blockIdx.x * 256 + threadIdx.x;      // 6*16384 = 98304
  int mat = gid >> 14, idx = gid & 16383;
  int cb = idx >> 11;
  int kk = (idx >> 9) & 3;
  int l  = (idx >> 3) & 63;
  int e  = idx & 7;
  int col = cb * 16 + (l & 15);
  int k   = kk * 32 + (l >> 4) * 8 + e;
  const float* src = (mat == 0) ? wga : (mat == 1) ? wa : (mat == 2) ? wgb
                   : (mat == 3) ? wb  : (mat == 4) ? wgo : wo;
  float v = src[k * 128 + col];
  unsigned short h = f2b(v);
  wP[gid]         = h;
  wP[98304 + gid] = f2b(v - b2f(h));
}

// ---------------- fused-LN helpers: 512-thread variant -----------------------
// row = t>>3 in [0,64), part = t&7 in [0,8); each thread covers 16 cols.
__device__ __forceinline__ void ln_sum4(const f32x4 v[4], float* red, int t) {
  float s = 0.f, ss = 0.f;
#pragma unroll
  for (int j = 0; j < 4; ++j)
#pragma unroll
    for (int e = 0; e < 4; ++e) { float x = v[j][e]; s += x; ss += x * x; }
  red[t * 2 + 0] = s;
  red[t * 2 + 1] = ss;
}

__device__ __forceinline__ void ln_gather8(const float* red, float* stats, int t) {
  if (t < 64) {
    float s = 0.f, ss = 0.f;
    for (int part = 0; part < 8; ++part) {
      s  += red[(t * 8 + part) * 2 + 0];
      ss += red[(t * 8 + part) * 2 + 1];
    }
    float mean = s * (1.0f / 128.0f);
    float var  = ss * (1.0f / 128.0f) - mean * mean;
    stats[t * 2 + 0] = mean;
    stats[t * 2 + 1] = rsqrtf(var + 1e-5f);
  }
}

__device__ __forceinline__ void ln_build4(const f32x4 v[4],
                                          const f32x4* gp, const f32x4* bp,
                                          const float* stats,
                                          char* Ah, char* Al, int row, int part) {
  const float mean = stats[row * 2], rstd = stats[row * 2 + 1];
  const int swz = (row & 7) << 4;
#pragma unroll
  for (int cc = 0; cc < 2; ++cc) {
    u16x8 ph, pl;
#pragma unroll
    for (int e = 0; e < 8; ++e) {
      int j = cc * 2 + (e >> 2), ee = e & 3;
      float x = (v[j][ee] - mean) * rstd * gp[j][ee] + bp[j][ee];
      unsigned short h = f2b(x);
      ph[e] = h;
      pl[e] = f2b(x - b2f(h));
    }
    int off = ((part * 2 + cc) * 16) ^ swz;
    *(u16x8*)(Ah + row * 256 + off) = ph;
    *(u16x8*)(Al + row * 256 + off) = pl;
  }
}

// ---------------- pass 1: MFMA (gb,b) + column-sum, 8-wave ------------------
__global__ __launch_bounds__(512, 4) void k1(
    const float* __restrict__ z,
    const float* __restrict__ lng, const float* __restrict__ lnb,
    const float* __restrict__ bgb, const float* __restrict__ bbv,
    const unsigned short* __restrict__ wT,
    float* __restrict__ partials)
{
  __shared__ __align__(16) char smem[ARENA_BYTES];
  float* zl    = (float*)smem;                 // merge only
  char*  Ah    = smem;
  char*  Al    = smem + 16384;
  float* red   = (float*)(smem + RED_OFF);
  float* stats = (float*)(smem + STATS_OFF);

  const int t = threadIdx.x;
  const int l = t & 63, w = t >> 6;            // wave id in [0,8)
  const int c15 = l & 15, kg = l >> 4;
  const int col0 = w * 16 + c15;               // wave w owns cols [w*16, w*16+16)
  const int row = t >> 3, part = t & 7;        // LN mapping (16 cols/thread)
  const int fl8 = l * 8;

  const unsigned short* wgh = wT + 2 * 16384;
  const unsigned short* wlh = wT + 3 * 16384;
  const unsigned short* wgl = wT + 98304 + 2 * 16384;
  const unsigned short* wll = wT + 98304 + 3 * 16384;
  const float vgb = bgb[col0];
  const float vlb = bbv[col0];
  const f32x4* gp = (const f32x4*)(lng + part * 16);
  const f32x4* bp = (const f32x4*)(lnb + part * 16);

  f32x4 breg[4];
#pragma unroll
  for (int mt = 0; mt < 4; ++mt) breg[mt] = (f32x4)(0.0f);

  for (int it = 0; it < 8; ++it) {
    const long base = (long)(blockIdx.x * 8 + it) * 64;

    // ---- fused LN(z): global load -> reg sum -> stats -> tiles ----
    f32x4 v[4];
    {
      const float* zp = z + (base + row) * 128 + part * 16;
#pragma unroll
      for (int j = 0; j < 4; ++j) v[j] = ((const f32x4*)zp)[j];
      ln_sum4(v, red, t);
    }
    __syncthreads();
    ln_gather8(red, stats, t);
    __syncthreads();
    ln_build4(v, gp, bp, stats, Ah, Al, row, part);
    __syncthreads();

    // ---- split GEMM (gb,b): per-wave 64x16 slice ----
    f32x4 g_[4], a_[4];
#pragma unroll
    for (int mt = 0; mt < 4; ++mt) { g_[mt] = (f32x4)(0.0f); a_[mt] = (f32x4)(0.0f); }
#pragma unroll
    for (int kk = 0; kk < 4; ++kk) {
      s16x8 ah[4], alo[4];
#pragma unroll
      for (int mt = 0; mt < 4; ++mt) {
        int ar = mt * 16 + c15;
        int off = ar * 256 + ((kk * 64 + kg * 16) ^ ((ar & 7) << 4));
        ah[mt]  = __builtin_bit_cast(s16x8, *(const u16x8*)(Ah + off));
        alo[mt] = __builtin_bit_cast(s16x8, *(const u16x8*)(Al + off));
      }
      int bofs = (w * 4 + kk) * 512 + fl8;
      LOADB(bgh, wgh + bofs);
      LOADB(bgl, wgl + bofs);
      LOADB(blh, wlh + bofs);
      LOADB(bll, wll + bofs);
#pragma unroll
      for (int mt = 0; mt < 4; ++mt) {
        g_[mt] = MFMAB(ah[mt],  bgh, g_[mt]);
        g_[mt] = MFMAB(alo[mt], bgh, g_[mt]);
        g_[mt] = MFMAB(ah[mt],  bgl, g_[mt]);
        a_[mt] = MFMAB(ah[mt],  blh, a_[mt]);
        a_[mt] = MFMAB(alo[mt], blh, a_[mt]);
        a_[mt] = MFMAB(ah[mt],  bll, a_[mt]);
      }
    }
#pragma unroll
    for (int mt = 0; mt < 4; ++mt)
#pragma unroll
      for (int r = 0; r < 4; ++r)
        breg[mt][r] += sigm(g_[mt][r] + vgb) * (a_[mt][r] + vlb);
    __syncthreads();   // GEMM tile reads done before next it's ln_build
  }

  float* sm = zl;
#pragma unroll
  for (int mt = 0; mt < 2; ++mt)
#pragma unroll
    for (int r = 0; r < 4; ++r) {
      int krow = mt * 16 + kg * 4 + r;
      sm[krow * 128 + col0] = breg[mt][r] + breg[mt + 2][r];
    }
  __syncthreads();
  for (int i = 0; i < 8; ++i) {
    int e = i * 512 + t;
    partials[(long)blockIdx.x * 4096 + e] = sm[e];
  }
}

// ---------------- reductions (r5 verbatim) ----------------------------------
__global__ void k_red_a(const float* __restrict__ pin, double* __restrict__ pout) {
  int gid = blockIdx.x * 256 + threadIdx.x;
  int e = gid & 4095, chunk = gid >> 12;
  const float* p = pin + (long)chunk * 16 * 4096 + e;
  double a0 = 0, a1 = 0, a2 = 0, a3 = 0;
#pragma unroll
  for (int i = 0; i < 16; i += 4) {
    a0 += (double)p[(i + 0) * 4096]; a1 += (double)p[(i + 1) * 4096];
    a2 += (double)p[(i + 2) * 4096]; a3 += (double)p[(i + 3) * 4096];
  }
  pout[gid] = (a0 + a1) + (a2 + a3);
}

__global__ void k_red_b(const double* __restrict__ pin, float* __restrict__ sfin) {
  int e = blockIdx.x * 256 + threadIdx.x;
  double a0 = 0, a1 = 0, a2 = 0, a3 = 0;
#pragma unroll
  for (int i = 0; i < 64; i += 4) {
    a0 += pin[(i + 0) * 4096 + e]; a1 += pin[(i + 1) * 4096 + e];
    a2 += pin[(i + 2) * 4096 + e]; a3 += pin[(i + 3) * 4096 + e];
  }
  sfin[e] = (float)((a0 + a1) + (a2 + a3));
}

// ---------------- pass 2: 512 threads, 8 waves, 64x16 slice per wave --------
__global__ __launch_bounds__(512, 4) void k2(
    const float* __restrict__ z,
    const float* __restrict__ lnig, const float* __restrict__ lnib,
    const float* __restrict__ bga, const float* __restrict__ ba,
    const float* __restrict__ bgo,
    const float* __restrict__ lnog, const float* __restrict__ lnob,
    const float* __restrict__ bo,
    const unsigned short* __restrict__ wT,
    const float* __restrict__ sfin,
    float* __restrict__ out)
{
  __shared__ __align__(16) char smem[ARENA_BYTES];
  float* zl    = (float*)smem;
  char*  Ah    = smem;
  char*  Al    = smem + 16384;
  float* red   = (float*)(smem + RED_OFF);
  float* stats = (float*)(smem + STATS_OFF);

  const int t = threadIdx.x;
  const int l = t & 63, w = t >> 6;            // wave id in [0,8)
  const int c15 = l & 15, kg = l >> 4;
  const int col0 = w * 16 + c15;               // wave w owns cols [w*16, w*16+16)
  const int row = t >> 3, part = t & 7;        // LN mapping (16 cols/thread)
  const int fl8 = l * 8;
  const long base = (long)blockIdx.x * 64;

  // ---- phase 1: fused LN(z) -> tiles ----
  {
    f32x4 v[4];
    const float* zp = z + (base + row) * 128 + part * 16;
#pragma unroll
    for (int j = 0; j < 4; ++j) v[j] = ((const f32x4*)zp)[j];
    ln_sum4(v, red, t);
    __syncthreads();
    ln_gather8(red, stats, t);
    __syncthreads();
    ln_build4(v, (const f32x4*)(lnig + part * 16), (const f32x4*)(lnib + part * 16),
              stats, Ah, Al, row, part);
  }
  __syncthreads();

  // ---- phase 2: GEMM pass A (ga, a) ----
  f32x4 ag[4];
  {
    const unsigned short* wgah = wT + 0 * 16384;
    const unsigned short* wah  = wT + 1 * 16384;
    const unsigned short* wgal = wT + 98304 + 0 * 16384;
    const unsigned short* wal  = wT + 98304 + 1 * 16384;
    f32x4 g_[4], a_[4];
#pragma unroll
    for (int mt = 0; mt < 4; ++mt) { g_[mt] = (f32x4)(0.0f); a_[mt] = (f32x4)(0.0f); }
#pragma unroll
    for (int kk = 0; kk < 4; ++kk) {
      s16x8 ah[4], alo[4];
#pragma unroll
      for (int mt = 0; mt < 4; ++mt) {
        int ar = mt * 16 + c15;
        int off = ar * 256 + ((kk * 64 + kg * 16) ^ ((ar & 7) << 4));
        ah[mt]  = __builtin_bit_cast(s16x8, *(const u16x8*)(Ah + off));
        alo[mt] = __builtin_bit_cast(s16x8, *(const u16x8*)(Al + off));
      }
      int bofs = (w * 4 + kk) * 512 + fl8;
      LOADB(g_h, wgah + bofs);
      LOADB(g_l, wgal + bofs);
      LOADB(a_h, wah + bofs);
      LOADB(a_l, wal + bofs);
#pragma unroll
      for (int mt = 0; mt < 4; ++mt) {
        g_[mt] = MFMAB(ah[mt],  g_h, g_[mt]);
        g_[mt] = MFMAB(alo[mt], g_h, g_[mt]);
        g_[mt] = MFMAB(ah[mt],  g_l, g_[mt]);
        a_[mt] = MFMAB(ah[mt],  a_h, a_[mt]);
        a_[mt] = MFMAB(alo[mt], a_h, a_[mt]);
        a_[mt] = MFMAB(ah[mt],  a_l, a_[mt]);
      }
    }
    float vga = bga[col0], vba = ba[col0];
#pragma unroll
    for (int mt = 0; mt < 4; ++mt)
#pragma unroll
      for (int r = 0; r < 4; ++r)
        ag[mt][r] = sigm(g_[mt][r] + vga) * (a_[mt][r] + vba);
  }

  // ---- phase 3: GEMM pass B: go ----
  f32x4 gg[4];
#pragma unroll
  for (int mt = 0; mt < 4; ++mt) gg[mt] = (f32x4)(0.0f);
  {
    const unsigned short* wgoh = wT + 4 * 16384;
    const unsigned short* wgol = wT + 98304 + 4 * 16384;
#pragma unroll
    for (int kk = 0; kk < 4; ++kk) {
      s16x8 ah[4], alo[4];
#pragma unroll
      for (int mt = 0; mt < 4; ++mt) {
        int ar = mt * 16 + c15;
        int off = ar * 256 + ((kk * 64 + kg * 16) ^ ((ar & 7) << 4));
        ah[mt]  = __builtin_bit_cast(s16x8, *(const u16x8*)(Ah + off));
        alo[mt] = __builtin_bit_cast(s16x8, *(const u16x8*)(Al + off));
      }
      int bofs = (w * 4 + kk) * 512 + fl8;
      LOADB(o_h, wgoh + bofs);
      LOADB(o_l, wgol + bofs);
#pragma unroll
      for (int mt = 0; mt < 4; ++mt) {
        gg[mt] = MFMAB(ah[mt],  o_h, gg[mt]);
        gg[mt] = MFMAB(alo[mt], o_h, gg[mt]);
        gg[mt] = MFMAB(ah[mt],  o_l, gg[mt]);
      }
    }
  }
  {
    float vgo = bgo[col0];
#pragma unroll
    for (int mt = 0; mt < 4; ++mt)
#pragma unroll
      for (int r = 0; r < 4; ++r)
        gg[mt][r] = sigm(gg[mt][r] + vgo);
  }
  __syncthreads();   // all tile reads done; arena reusable as f32 zl

  // ---- phase 4: kv = a * s[k] -> zl ----
#pragma unroll
  for (int mt = 0; mt < 4; ++mt)
#pragma unroll
    for (int r = 0; r < 4; ++r) {
      int rw = mt * 16 + kg * 4 + r;
      zl[rw * ZL_STRIDE + col0] = ag[mt][r] * sfin[(rw & 31) * 128 + col0];
    }
  __syncthreads();   // kv visible

  // ---- phase 5: fused LN(kv) -> tiles ----
  {
    f32x4 v[4];
    const f32x4* kp = (const f32x4*)(zl + row * ZL_STRIDE + part * 16);
#pragma unroll
    for (int j = 0; j < 4; ++j) v[j] = kp[j];
    ln_sum4(v, red, t);
    __syncthreads();
    ln_gather8(red, stats, t);
    __syncthreads();   // stats visible; all kv raw reads complete
    ln_build4(v, (const f32x4*)(lnog + part * 16), (const f32x4*)(lnob + part * 16),
              stats, Ah, Al, row, part);
  }
  __syncthreads();

  // ---- phase 6: w_o GEMM ----
  f32x4 acc[4];
#pragma unroll
  for (int mt = 0; mt < 4; ++mt) acc[mt] = (f32x4)(0.0f);
  {
    const unsigned short* woh = wT + 5 * 16384;
    const unsigned short* wol = wT + 98304 + 5 * 16384;
#pragma unroll
    for (int kk = 0; kk < 4; ++kk) {
      s16x8 ah[4], alo[4];
#pragma unroll
      for (int mt = 0; mt < 4; ++mt) {
        int ar = mt * 16 + c15;
        int off = ar * 256 + ((kk * 64 + kg * 16) ^ ((ar & 7) << 4));
        ah[mt]  = __builtin_bit_cast(s16x8, *(const u16x8*)(Ah + off));
        alo[mt] = __builtin_bit_cast(s16x8, *(const u16x8*)(Al + off));
      }
      int bofs = (w * 4 + kk) * 512 + fl8;
      LOADB(o_h, woh + bofs);
      LOADB(o_l, wol + bofs);
#pragma unroll
      for (int mt = 0; mt < 4; ++mt) {
        acc[mt] = MFMAB(ah[mt],  o_h, acc[mt]);
        acc[mt] = MFMAB(alo[mt], o_h, acc[mt]);
        acc[mt] = MFMAB(ah[mt],  o_l, acc[mt]);
      }
    }
  }

  // ---- phase 7: out = sigm(go) * (acc + b_o) ----
  {
    float bov = bo[col0];
#pragma unroll
    for (int mt = 0; mt < 4; ++mt)
#pragma unroll
      for (int r = 0; r < 4; ++r) {
        int rw = mt * 16 + kg * 4 + r;
        out[(base + rw) * 128 + col0] = gg[mt][r] * (acc[mt][r] + bov);
      }
  }
}

// ---------------------------------------------------------------------------
extern "C" void kernel_launch(void* const* d_in, const int* in_sizes, int n_in,
                              void* d_out, int out_size, void* d_ws, size_t ws_size,
                              hipStream_t stream) {
  const float* z    = (const float*)d_in[0];
  const float* lnig = (const float*)d_in[1];
  const float* lnib = (const float*)d_in[2];
  const float* w_a  = (const float*)d_in[3];
  const float* b_a  = (const float*)d_in[4];
  const float* w_ga = (const float*)d_in[5];
  const float* b_ga = (const float*)d_in[6];
  const float* w_b  = (const float*)d_in[7];
  const float* b_b  = (const float*)d_in[8];
  const float* w_gb = (const float*)d_in[9];
  const float* b_gb = (const float*)d_in[10];
  const float* lnog = (const float*)d_in[11];
  const float* lnob = (const float*)d_in[12];
  const float* w_go = (const float*)d_in[13];
  const float* b_go = (const float*)d_in[14];
  const float* w_o  = (const float*)d_in[15];
  const float* b_o  = (const float*)d_in[16];

  // ws: sfin 16KB @0, wP 384KB @16384
  float* sfin = (float*)d_ws;
  unsigned short* wT = (unsigned short*)((char*)d_ws + 16384);

  // big scratch in d_out (fully overwritten by k2):
  float*  partials  = (float*)d_out;                        // 16 MB
  double* partials2 = (double*)((char*)d_out + 16777216);   //  2 MB

  k_pack<<<384, 256, 0, stream>>>(w_ga, w_a, w_gb, w_b, w_go, w_o, wT);
  k1<<<1024, 512, 0, stream>>>(z, lnig, lnib, b_gb, b_b, wT, partials);
  k_red_a<<<1024, 256, 0, stream>>>(partials, partials2);
  k_red_b<<<16, 256, 0, stream>>>(partials2, sfin);
  k2<<<8192, 512, 0, stream>>>(z, lnig, lnib,
                               b_ga, b_a, b_go, lnog, lnob, b_o,
                               wT, sfin, (float*)d_out);
}

// Round 4
// 471.378 us; speedup vs baseline: 1.1068x; 1.1068x over previous
//
#include <hip/hip_runtime.h>
#include <stdint.h>

// ---------------------------------------------------------------------------
// Round 15: r13 structure restored + hardware bf16 conversion.
//   - k1 reverted to r13-exact (256 thr / 4 waves; the r14 8-wave port
//     regressed ~26us: k1 is barrier/latency-bound, not occupancy-bound).
//   - f2b redefined as a plain __bf16 cast (fptrunc): compiler emits
//     gfx950 v_cvt_pk_bf16_f32 (hardware RNE, 2 cvt/inst) instead of the
//     4-op software-RNE bit sequence. Cuts ~320 VALU-ops/thread in k2's
//     two LN builds (VALUBusy 51% is k2's limiting pipe). Hardware RNE is
//     bit-identical to software RNE for finite values -> same results.
//   - k2, reductions, pack: r13 verbatim.
// ---------------------------------------------------------------------------

typedef __attribute__((ext_vector_type(8))) short          s16x8;
typedef __attribute__((ext_vector_type(8))) unsigned short u16x8;
typedef __attribute__((ext_vector_type(4))) float          f32x4;

#define MFMAB(A, B, C) __builtin_amdgcn_mfma_f32_16x16x32_bf16((A), (B), (C), 0, 0, 0)

__device__ __forceinline__ unsigned short f2b(float x) {   // f32 -> bf16 RNE (HW cvt)
  return __builtin_bit_cast(unsigned short, (__bf16)x);
}
__device__ __forceinline__ float b2f(unsigned short u) {
  return __builtin_bit_cast(float, (uint32_t)u << 16);
}
__device__ __forceinline__ float sigm(float x) { return 1.0f / (1.0f + __expf(-x)); }

#define LOADB(dst, ptr) s16x8 dst = __builtin_bit_cast(s16x8, *(const u16x8*)(ptr))

#define ZL_STRIDE 132   // floats per LDS row (16B-aligned rows)

// k1 arena (36352 B): zl f32[64][132] @0; Ah @0 (aliases), Al @16384;
// red @33792 (256 thr * 2 f), stats @35840.
#define ARENA1_BYTES 36352
#define RED1_OFF     33792
#define STATS1_OFF   35840

// k2 arena (38400 B): zl f32[64][132] @0; Ah @0, Al @16384;
// red @33792 (512 thr * 2 f = 4096 B), stats @37888 (512 B).
#define ARENA2_BYTES 38400
#define RED2_OFF     33792
#define STATS2_OFF   37888

// ---------------- weight pack: fragment-ordered -----------------------------
// hi: wP[mat*16384 + cb*2048 + kk*512 + l*8 + e]; lo at +98304.
// value = src[(kk*32 + (l>>4)*8 + e)*128 + cb*16 + (l&15)]
// mats: 0=ga 1=a 2=gb 3=b 4=go 5=o
__global__ void k_pack(const float* __restrict__ wga, const float* __restrict__ wa,
                       const float* __restrict__ wgb, const float* __restrict__ wb,
                       const float* __restrict__ wgo, const float* __restrict__ wo,
                       unsigned short* __restrict__ wP) {
  int gid = blockIdx.x * 256 + threadIdx.x;      // 6*16384 = 98304
  int mat = gid >> 14, idx = gid & 16383;
  int cb = idx >> 11;
  int kk = (idx >> 9) & 3;
  int l  = (idx >> 3) & 63;
  int e  = idx & 7;
  int col = cb * 16 + (l & 15);
  int k   = kk * 32 + (l >> 4) * 8 + e;
  const float* src = (mat == 0) ? wga : (mat == 1) ? wa : (mat == 2) ? wgb
                   : (mat == 3) ? wb  : (mat == 4) ? wgo : wo;
  float v = src[k * 128 + col];
  unsigned short h = f2b(v);
  wP[gid]         = h;
  wP[98304 + gid] = f2b(v - b2f(h));
}

// ---------------- fused-LN helpers: 256-thread (k1) variant ------------------
__device__ __forceinline__ void ln_sum(const f32x4 v[8], float* red, int t) {
  float s = 0.f, ss = 0.f;
#pragma unroll
  for (int j = 0; j < 8; ++j)
#pragma unroll
    for (int e = 0; e < 4; ++e) { float x = v[j][e]; s += x; ss += x * x; }
  red[t * 2 + 0] = s;
  red[t * 2 + 1] = ss;
}

__device__ __forceinline__ void ln_gather(const float* red, float* stats, int t) {
  if (t < 64) {
    float s = 0.f, ss = 0.f;
    for (int part = 0; part < 4; ++part) {
      s  += red[(t * 4 + part) * 2 + 0];
      ss += red[(t * 4 + part) * 2 + 1];
    }
    float mean = s * (1.0f / 128.0f);
    float var  = ss * (1.0f / 128.0f) - mean * mean;
    stats[t * 2 + 0] = mean;
    stats[t * 2 + 1] = rsqrtf(var + 1e-5f);
  }
}

__device__ __forceinline__ void ln_build(const f32x4 v[8],
                                         const f32x4* gp, const f32x4* bp,
                                         const float* stats,
                                         char* Ah, char* Al, int row, int part) {
  const float mean = stats[row * 2], rstd = stats[row * 2 + 1];
  const int swz = (row & 7) << 4;
#pragma unroll
  for (int cc = 0; cc < 4; ++cc) {
    u16x8 ph, pl;
#pragma unroll
    for (int e = 0; e < 8; ++e) {
      int j = cc * 2 + (e >> 2), ee = e & 3;
      float x = (v[j][ee] - mean) * rstd * gp[j][ee] + bp[j][ee];
      unsigned short h = f2b(x);
      ph[e] = h;
      pl[e] = f2b(x - b2f(h));
    }
    int off = ((part * 4 + cc) * 16) ^ swz;
    *(u16x8*)(Ah + row * 256 + off) = ph;
    *(u16x8*)(Al + row * 256 + off) = pl;
  }
}

// ---------------- fused-LN helpers: 512-thread (k2) variant ------------------
// row = t>>3 in [0,64), part = t&7 in [0,8); each thread covers 16 cols.
__device__ __forceinline__ void ln_sum4(const f32x4 v[4], float* red, int t) {
  float s = 0.f, ss = 0.f;
#pragma unroll
  for (int j = 0; j < 4; ++j)
#pragma unroll
    for (int e = 0; e < 4; ++e) { float x = v[j][e]; s += x; ss += x * x; }
  red[t * 2 + 0] = s;
  red[t * 2 + 1] = ss;
}

__device__ __forceinline__ void ln_gather8(const float* red, float* stats, int t) {
  if (t < 64) {
    float s = 0.f, ss = 0.f;
    for (int part = 0; part < 8; ++part) {
      s  += red[(t * 8 + part) * 2 + 0];
      ss += red[(t * 8 + part) * 2 + 1];
    }
    float mean = s * (1.0f / 128.0f);
    float var  = ss * (1.0f / 128.0f) - mean * mean;
    stats[t * 2 + 0] = mean;
    stats[t * 2 + 1] = rsqrtf(var + 1e-5f);
  }
}

__device__ __forceinline__ void ln_build4(const f32x4 v[4],
                                          const f32x4* gp, const f32x4* bp,
                                          const float* stats,
                                          char* Ah, char* Al, int row, int part) {
  const float mean = stats[row * 2], rstd = stats[row * 2 + 1];
  const int swz = (row & 7) << 4;
#pragma unroll
  for (int cc = 0; cc < 2; ++cc) {
    u16x8 ph, pl;
#pragma unroll
    for (int e = 0; e < 8; ++e) {
      int j = cc * 2 + (e >> 2), ee = e & 3;
      float x = (v[j][ee] - mean) * rstd * gp[j][ee] + bp[j][ee];
      unsigned short h = f2b(x);
      ph[e] = h;
      pl[e] = f2b(x - b2f(h));
    }
    int off = ((part * 2 + cc) * 16) ^ swz;
    *(u16x8*)(Ah + row * 256 + off) = ph;
    *(u16x8*)(Al + row * 256 + off) = pl;
  }
}

// ---------------- pass 1: MFMA (gb,b) + column-sum reduction (r13 exact) ----
__global__ __launch_bounds__(256) void k1(
    const float* __restrict__ z,
    const float* __restrict__ lng, const float* __restrict__ lnb,
    const float* __restrict__ bgb, const float* __restrict__ bbv,
    const unsigned short* __restrict__ wT,
    float* __restrict__ partials)
{
  __shared__ __align__(16) char smem[ARENA1_BYTES];
  float* zl    = (float*)smem;                 // merge only
  char*  Ah    = smem;
  char*  Al    = smem + 16384;
  float* red   = (float*)(smem + RED1_OFF);
  float* stats = (float*)(smem + STATS1_OFF);

  const int t = threadIdx.x;
  const int l = t & 63, wv = t >> 6;
  const int c15 = l & 15, kg = l >> 4;
  const int col0 = wv * 32 + c15;
  const int row = t >> 2, part = t & 3;        // LN mapping
  const int fl8 = l * 8;                        // fragment lane offset
  const int wv2 = wv * 2;

  const unsigned short* wgh = wT + 2 * 16384;
  const unsigned short* wlh = wT + 3 * 16384;
  const unsigned short* wgl = wT + 98304 + 2 * 16384;
  const unsigned short* wll = wT + 98304 + 3 * 16384;
  const float vgb0 = bgb[col0], vgb1 = bgb[col0 + 16];
  const float vlb0 = bbv[col0], vlb1 = bbv[col0 + 16];
  const f32x4* gp = (const f32x4*)(lng + part * 32);
  const f32x4* bp = (const f32x4*)(lnb + part * 32);

  f32x4 breg[4][2];
#pragma unroll
  for (int mt = 0; mt < 4; ++mt)
#pragma unroll
    for (int nt = 0; nt < 2; ++nt) breg[mt][nt] = (f32x4)(0.0f);

  for (int it = 0; it < 8; ++it) {
    const long base = (long)(blockIdx.x * 8 + it) * 64;

    // ---- fused LN(z): global load -> reg sum -> stats -> tiles ----
    f32x4 v[8];
    {
      const float* zp = z + (base + row) * 128 + part * 32;
#pragma unroll
      for (int j = 0; j < 8; ++j) v[j] = ((const f32x4*)zp)[j];
      ln_sum(v, red, t);
    }
    __syncthreads();
    ln_gather(red, stats, t);
    __syncthreads();
    ln_build(v, gp, bp, stats, Ah, Al, row, part);
    __syncthreads();

    // ---- split GEMM (gb,b): coalesced fragment loads ----
    f32x4 ag[4][2], al_[4][2];
#pragma unroll
    for (int mt = 0; mt < 4; ++mt)
#pragma unroll
      for (int nt = 0; nt < 2; ++nt) { ag[mt][nt] = (f32x4)(0.0f); al_[mt][nt] = (f32x4)(0.0f); }
#pragma unroll
    for (int kk = 0; kk < 4; ++kk) {
      s16x8 ah[4], alo[4];
#pragma unroll
      for (int mt = 0; mt < 4; ++mt) {
        int ar = mt * 16 + c15;
        int off = ar * 256 + ((kk * 64 + kg * 16) ^ ((ar & 7) << 4));
        ah[mt]  = __builtin_bit_cast(s16x8, *(const u16x8*)(Ah + off));
        alo[mt] = __builtin_bit_cast(s16x8, *(const u16x8*)(Al + off));
      }
#pragma unroll
      for (int nt = 0; nt < 2; ++nt) {
        int bofs = ((wv2 + nt) * 4 + kk) * 512 + fl8;
        LOADB(bgh, wgh + bofs);
        LOADB(bgl, wgl + bofs);
        LOADB(blh, wlh + bofs);
        LOADB(bll, wll + bofs);
#pragma unroll
        for (int mt = 0; mt < 4; ++mt) {
          ag[mt][nt]  = MFMAB(ah[mt],  bgh, ag[mt][nt]);
          ag[mt][nt]  = MFMAB(alo[mt], bgh, ag[mt][nt]);
          ag[mt][nt]  = MFMAB(ah[mt],  bgl, ag[mt][nt]);
          al_[mt][nt] = MFMAB(ah[mt],  blh, al_[mt][nt]);
          al_[mt][nt] = MFMAB(alo[mt], blh, al_[mt][nt]);
          al_[mt][nt] = MFMAB(ah[mt],  bll, al_[mt][nt]);
        }
      }
    }
#pragma unroll
    for (int nt = 0; nt < 2; ++nt) {
      float vg = nt ? vgb1 : vgb0, vl = nt ? vlb1 : vlb0;
#pragma unroll
      for (int mt = 0; mt < 4; ++mt)
#pragma unroll
        for (int r = 0; r < 4; ++r)
          breg[mt][nt][r] += sigm(ag[mt][nt][r] + vg) * (al_[mt][nt][r] + vl);
    }
  }

  __syncthreads();
  float* sm = zl;
#pragma unroll
  for (int mt = 0; mt < 2; ++mt)
#pragma unroll
    for (int nt = 0; nt < 2; ++nt) {
      int col = col0 + nt * 16;
#pragma unroll
      for (int r = 0; r < 4; ++r) {
        int krow = mt * 16 + kg * 4 + r;
        sm[krow * 128 + col] = breg[mt][nt][r] + breg[mt + 2][nt][r];
      }
    }
  __syncthreads();
  for (int i = 0; i < 16; ++i) {
    int e = i * 256 + t;
    partials[(long)blockIdx.x * 4096 + e] = sm[e];
  }
}

// ---------------- reductions (r5 verbatim) ----------------------------------
__global__ void k_red_a(const float* __restrict__ pin, double* __restrict__ pout) {
  int gid = blockIdx.x * 256 + threadIdx.x;
  int e = gid & 4095, chunk = gid >> 12;
  const float* p = pin + (long)chunk * 16 * 4096 + e;
  double a0 = 0, a1 = 0, a2 = 0, a3 = 0;
#pragma unroll
  for (int i = 0; i < 16; i += 4) {
    a0 += (double)p[(i + 0) * 4096]; a1 += (double)p[(i + 1) * 4096];
    a2 += (double)p[(i + 2) * 4096]; a3 += (double)p[(i + 3) * 4096];
  }
  pout[gid] = (a0 + a1) + (a2 + a3);
}

__global__ void k_red_b(const double* __restrict__ pin, float* __restrict__ sfin) {
  int e = blockIdx.x * 256 + threadIdx.x;
  double a0 = 0, a1 = 0, a2 = 0, a3 = 0;
#pragma unroll
  for (int i = 0; i < 64; i += 4) {
    a0 += pin[(i + 0) * 4096 + e]; a1 += pin[(i + 1) * 4096 + e];
    a2 += pin[(i + 2) * 4096 + e]; a3 += pin[(i + 3) * 4096 + e];
  }
  sfin[e] = (float)((a0 + a1) + (a2 + a3));
}

// ---------------- pass 2: 512 threads, 8 waves, 64x16 slice per wave --------
__global__ __launch_bounds__(512, 4) void k2(
    const float* __restrict__ z,
    const float* __restrict__ lnig, const float* __restrict__ lnib,
    const float* __restrict__ bga, const float* __restrict__ ba,
    const float* __restrict__ bgo,
    const float* __restrict__ lnog, const float* __restrict__ lnob,
    const float* __restrict__ bo,
    const unsigned short* __restrict__ wT,
    const float* __restrict__ sfin,
    float* __restrict__ out)
{
  __shared__ __align__(16) char smem[ARENA2_BYTES];
  float* zl    = (float*)smem;
  char*  Ah    = smem;
  char*  Al    = smem + 16384;
  float* red   = (float*)(smem + RED2_OFF);
  float* stats = (float*)(smem + STATS2_OFF);

  const int t = threadIdx.x;
  const int l = t & 63, w = t >> 6;            // wave id in [0,8)
  const int c15 = l & 15, kg = l >> 4;
  const int col0 = w * 16 + c15;               // wave w owns cols [w*16, w*16+16)
  const int row = t >> 3, part = t & 7;        // LN mapping (16 cols/thread)
  const int fl8 = l * 8;
  const long base = (long)blockIdx.x * 64;

  // ---- phase 1: fused LN(z) -> tiles ----
  {
    f32x4 v[4];
    const float* zp = z + (base + row) * 128 + part * 16;
#pragma unroll
    for (int j = 0; j < 4; ++j) v[j] = ((const f32x4*)zp)[j];
    ln_sum4(v, red, t);
    __syncthreads();
    ln_gather8(red, stats, t);
    __syncthreads();
    ln_build4(v, (const f32x4*)(lnig + part * 16), (const f32x4*)(lnib + part * 16),
              stats, Ah, Al, row, part);
  }
  __syncthreads();

  // ---- phase 2: GEMM pass A (ga, a) ----
  f32x4 ag[4];
  {
    const unsigned short* wgah = wT + 0 * 16384;
    const unsigned short* wah  = wT + 1 * 16384;
    const unsigned short* wgal = wT + 98304 + 0 * 16384;
    const unsigned short* wal  = wT + 98304 + 1 * 16384;
    f32x4 g_[4], a_[4];
#pragma unroll
    for (int mt = 0; mt < 4; ++mt) { g_[mt] = (f32x4)(0.0f); a_[mt] = (f32x4)(0.0f); }
#pragma unroll
    for (int kk = 0; kk < 4; ++kk) {
      s16x8 ah[4], alo[4];
#pragma unroll
      for (int mt = 0; mt < 4; ++mt) {
        int ar = mt * 16 + c15;
        int off = ar * 256 + ((kk * 64 + kg * 16) ^ ((ar & 7) << 4));
        ah[mt]  = __builtin_bit_cast(s16x8, *(const u16x8*)(Ah + off));
        alo[mt] = __builtin_bit_cast(s16x8, *(const u16x8*)(Al + off));
      }
      int bofs = (w * 4 + kk) * 512 + fl8;
      LOADB(g_h, wgah + bofs);
      LOADB(g_l, wgal + bofs);
      LOADB(a_h, wah + bofs);
      LOADB(a_l, wal + bofs);
#pragma unroll
      for (int mt = 0; mt < 4; ++mt) {
        g_[mt] = MFMAB(ah[mt],  g_h, g_[mt]);
        g_[mt] = MFMAB(alo[mt], g_h, g_[mt]);
        g_[mt] = MFMAB(ah[mt],  g_l, g_[mt]);
        a_[mt] = MFMAB(ah[mt],  a_h, a_[mt]);
        a_[mt] = MFMAB(alo[mt], a_h, a_[mt]);
        a_[mt] = MFMAB(ah[mt],  a_l, a_[mt]);
      }
    }
    float vga = bga[col0], vba = ba[col0];
#pragma unroll
    for (int mt = 0; mt < 4; ++mt)
#pragma unroll
      for (int r = 0; r < 4; ++r)
        ag[mt][r] = sigm(g_[mt][r] + vga) * (a_[mt][r] + vba);
  }

  // ---- phase 3: GEMM pass B: go ----
  f32x4 gg[4];
#pragma unroll
  for (int mt = 0; mt < 4; ++mt) gg[mt] = (f32x4)(0.0f);
  {
    const unsigned short* wgoh = wT + 4 * 16384;
    const unsigned short* wgol = wT + 98304 + 4 * 16384;
#pragma unroll
    for (int kk = 0; kk < 4; ++kk) {
      s16x8 ah[4], alo[4];
#pragma unroll
      for (int mt = 0; mt < 4; ++mt) {
        int ar = mt * 16 + c15;
        int off = ar * 256 + ((kk * 64 + kg * 16) ^ ((ar & 7) << 4));
        ah[mt]  = __builtin_bit_cast(s16x8, *(const u16x8*)(Ah + off));
        alo[mt] = __builtin_bit_cast(s16x8, *(const u16x8*)(Al + off));
      }
      int bofs = (w * 4 + kk) * 512 + fl8;
      LOADB(o_h, wgoh + bofs);
      LOADB(o_l, wgol + bofs);
#pragma unroll
      for (int mt = 0; mt < 4; ++mt) {
        gg[mt] = MFMAB(ah[mt],  o_h, gg[mt]);
        gg[mt] = MFMAB(alo[mt], o_h, gg[mt]);
        gg[mt] = MFMAB(ah[mt],  o_l, gg[mt]);
      }
    }
  }
  {
    float vgo = bgo[col0];
#pragma unroll
    for (int mt = 0; mt < 4; ++mt)
#pragma unroll
      for (int r = 0; r < 4; ++r)
        gg[mt][r] = sigm(gg[mt][r] + vgo);
  }
  __syncthreads();   // all tile reads done; arena reusable as f32 zl

  // ---- phase 4: kv = a * s[k] -> zl ----
#pragma unroll
  for (int mt = 0; mt < 4; ++mt)
#pragma unroll
    for (int r = 0; r < 4; ++r) {
      int rw = mt * 16 + kg * 4 + r;
      zl[rw * ZL_STRIDE + col0] = ag[mt][r] * sfin[(rw & 31) * 128 + col0];
    }
  __syncthreads();   // kv visible

  // ---- phase 5: fused LN(kv) -> tiles ----
  {
    f32x4 v[4];
    const f32x4* kp = (const f32x4*)(zl + row * ZL_STRIDE + part * 16);
#pragma unroll
    for (int j = 0; j < 4; ++j) v[j] = kp[j];
    ln_sum4(v, red, t);
    __syncthreads();
    ln_gather8(red, stats, t);
    __syncthreads();   // stats visible; all kv raw reads complete
    ln_build4(v, (const f32x4*)(lnog + part * 16), (const f32x4*)(lnob + part * 16),
              stats, Ah, Al, row, part);
  }
  __syncthreads();

  // ---- phase 6: w_o GEMM ----
  f32x4 acc[4];
#pragma unroll
  for (int mt = 0; mt < 4; ++mt) acc[mt] = (f32x4)(0.0f);
  {
    const unsigned short* woh = wT + 5 * 16384;
    const unsigned short* wol = wT + 98304 + 5 * 16384;
#pragma unroll
    for (int kk = 0; kk < 4; ++kk) {
      s16x8 ah[4], alo[4];
#pragma unroll
      for (int mt = 0; mt < 4; ++mt) {
        int ar = mt * 16 + c15;
        int off = ar * 256 + ((kk * 64 + kg * 16) ^ ((ar & 7) << 4));
        ah[mt]  = __builtin_bit_cast(s16x8, *(const u16x8*)(Ah + off));
        alo[mt] = __builtin_bit_cast(s16x8, *(const u16x8*)(Al + off));
      }
      int bofs = (w * 4 + kk) * 512 + fl8;
      LOADB(o_h, woh + bofs);
      LOADB(o_l, wol + bofs);
#pragma unroll
      for (int mt = 0; mt < 4; ++mt) {
        acc[mt] = MFMAB(ah[mt],  o_h, acc[mt]);
        acc[mt] = MFMAB(alo[mt], o_h, acc[mt]);
        acc[mt] = MFMAB(ah[mt],  o_l, acc[mt]);
      }
    }
  }

  // ---- phase 7: out = sigm(go) * (acc + b_o) ----
  {
    float bov = bo[col0];
#pragma unroll
    for (int mt = 0; mt < 4; ++mt)
#pragma unroll
      for (int r = 0; r < 4; ++r) {
        int rw = mt * 16 + kg * 4 + r;
        out[(base + rw) * 128 + col0] = gg[mt][r] * (acc[mt][r] + bov);
      }
  }
}

// ---------------------------------------------------------------------------
extern "C" void kernel_launch(void* const* d_in, const int* in_sizes, int n_in,
                              void* d_out, int out_size, void* d_ws, size_t ws_size,
                              hipStream_t stream) {
  const float* z    = (const float*)d_in[0];
  const float* lnig = (const float*)d_in[1];
  const float* lnib = (const float*)d_in[2];
  const float* w_a  = (const float*)d_in[3];
  const float* b_a  = (const float*)d_in[4];
  const float* w_ga = (const float*)d_in[5];
  const float* b_ga = (const float*)d_in[6];
  const float* w_b  = (const float*)d_in[7];
  const float* b_b  = (const float*)d_in[8];
  const float* w_gb = (const float*)d_in[9];
  const float* b_gb = (const float*)d_in[10];
  const float* lnog = (const float*)d_in[11];
  const float* lnob = (const float*)d_in[12];
  const float* w_go = (const float*)d_in[13];
  const float* b_go = (const float*)d_in[14];
  const float* w_o  = (const float*)d_in[15];
  const float* b_o  = (const float*)d_in[16];

  // ws: sfin 16KB @0, wP 384KB @16384
  float* sfin = (float*)d_ws;
  unsigned short* wT = (unsigned short*)((char*)d_ws + 16384);

  // big scratch in d_out (fully overwritten by k2):
  float*  partials  = (float*)d_out;                        // 16 MB
  double* partials2 = (double*)((char*)d_out + 16777216);   //  2 MB

  k_pack<<<384, 256, 0, stream>>>(w_ga, w_a, w_gb, w_b, w_go, w_o, wT);
  k1<<<1024, 256, 0, stream>>>(z, lnig, lnib, b_gb, b_b, wT, partials);
  k_red_a<<<1024, 256, 0, stream>>>(partials, partials2);
  k_red_b<<<16, 256, 0, stream>>>(partials2, sfin);
  k2<<<8192, 512, 0, stream>>>(z, lnig, lnib,
                               b_ga, b_a, b_go, lnog, lnob, b_o,
                               wT, sfin, (float*)d_out);
}

// Round 6
// 459.582 us; speedup vs baseline: 1.1352x; 1.0257x over previous
//
#include <hip/hip_runtime.h>
#include <stdint.h>

// ---------------------------------------------------------------------------
// Round 17: r15 base + parallel LDS LN-stats (no __shfl; r16's shfl version
// failed numerically and is abandoned).
//   - LN stats: every thread reads its row's GRP partials from `red` in
//     ascending order and computes mean/rstd locally — identical values,
//     identical FP order as r15's t<64 gather -> bit-exact, but no serial
//     section, no stats[] round-trip, one less barrier per LN.
//   - red[] moved to a DISJOINT LDS region (k1 @32768, k2 @33792) so tile
//     writes never alias concurrent red reads.
//   - Barriers: k2 8 -> 6, k1 3 -> 2 per iteration.
//   - GEMM phases, weight path, HW f2b cvt: r15 verbatim.
// ---------------------------------------------------------------------------

typedef __attribute__((ext_vector_type(8))) short          s16x8;
typedef __attribute__((ext_vector_type(8))) unsigned short u16x8;
typedef __attribute__((ext_vector_type(4))) float          f32x4;

#define MFMAB(A, B, C) __builtin_amdgcn_mfma_f32_16x16x32_bf16((A), (B), (C), 0, 0, 0)

__device__ __forceinline__ unsigned short f2b(float x) {   // f32 -> bf16 RNE (HW cvt)
  return __builtin_bit_cast(unsigned short, (__bf16)x);
}
__device__ __forceinline__ float b2f(unsigned short u) {
  return __builtin_bit_cast(float, (uint32_t)u << 16);
}
__device__ __forceinline__ float sigm(float x) { return 1.0f / (1.0f + __expf(-x)); }

#define LOADB(dst, ptr) s16x8 dst = __builtin_bit_cast(s16x8, *(const u16x8*)(ptr))

#define ZL_STRIDE 132   // floats per LDS row (16B-aligned rows)

// k1 arena (34816 B): tiles Ah @0 / Al @16384 (zl merge aliases Ah);
// red @32768 (256 thr * 8 B).
#define ARENA1_BYTES 34816
#define RED1_OFF     32768
// k2 arena (37888 B): zl f32[64][132] @0; Ah @0, Al @16384 (alias zl);
// red @33792 (512 thr * 8 B).
#define ARENA2_BYTES 37888
#define RED2_OFF     33792

// ---------------- weight pack: fragment-ordered -----------------------------
// hi: wP[mat*16384 + cb*2048 + kk*512 + l*8 + e]; lo at +98304.
// value = src[(kk*32 + (l>>4)*8 + e)*128 + cb*16 + (l&15)]
// mats: 0=ga 1=a 2=gb 3=b 4=go 5=o
__global__ void k_pack(const float* __restrict__ wga, const float* __restrict__ wa,
                       const float* __restrict__ wgb, const float* __restrict__ wb,
                       const float* __restrict__ wgo, const float* __restrict__ wo,
                       unsigned short* __restrict__ wP) {
  int gid = blockIdx.x * 256 + threadIdx.x;      // 6*16384 = 98304
  int mat = gid >> 14, idx = gid & 16383;
  int cb = idx >> 11;
  int kk = (idx >> 9) & 3;
  int l  = (idx >> 3) & 63;
  int e  = idx & 7;
  int col = cb * 16 + (l & 15);
  int k   = kk * 32 + (l >> 4) * 8 + e;
  const float* src = (mat == 0) ? wga : (mat == 1) ? wa : (mat == 2) ? wgb
                   : (mat == 3) ? wb  : (mat == 4) ? wgo : wo;
  float v = src[k * 128 + col];
  unsigned short h = f2b(v);
  wP[gid]         = h;
  wP[98304 + gid] = f2b(v - b2f(h));
}

// ---------------- fused-LN helpers ------------------------------------------
// Parallel stats: each thread reads its row's GRP partials in ascending part
// order — identical values & FP order as the old t<64 gather (bit-exact),
// computed redundantly by all threads of the row (deterministic).
template<int GRP>
__device__ __forceinline__ void ln_stats_lds(const float* red, int row,
                                             float& mean, float& rstd) {
  float S = 0.f, SS = 0.f;
#pragma unroll
  for (int p = 0; p < GRP; ++p) {
    S  += red[(row * GRP + p) * 2 + 0];
    SS += red[(row * GRP + p) * 2 + 1];
  }
  mean = S * (1.0f / 128.0f);
  const float var = SS * (1.0f / 128.0f) - mean * mean;
  rstd = rsqrtf(var + 1e-5f);
}

// 256-thread (k1) variant: row = t>>2, part = t&3, 32 cols/thread.
__device__ __forceinline__ void ln_sum(const f32x4 v[8], float* red, int t) {
  float s = 0.f, ss = 0.f;
#pragma unroll
  for (int j = 0; j < 8; ++j)
#pragma unroll
    for (int e = 0; e < 4; ++e) { float x = v[j][e]; s += x; ss += x * x; }
  red[t * 2 + 0] = s;
  red[t * 2 + 1] = ss;
}

__device__ __forceinline__ void ln_build(const f32x4 v[8],
                                         const f32x4* gp, const f32x4* bp,
                                         float mean, float rstd,
                                         char* Ah, char* Al, int row, int part) {
  const int swz = (row & 7) << 4;
#pragma unroll
  for (int cc = 0; cc < 4; ++cc) {
    u16x8 ph, pl;
#pragma unroll
    for (int e = 0; e < 8; ++e) {
      int j = cc * 2 + (e >> 2), ee = e & 3;
      float x = (v[j][ee] - mean) * rstd * gp[j][ee] + bp[j][ee];
      unsigned short h = f2b(x);
      ph[e] = h;
      pl[e] = f2b(x - b2f(h));
    }
    int off = ((part * 4 + cc) * 16) ^ swz;
    *(u16x8*)(Ah + row * 256 + off) = ph;
    *(u16x8*)(Al + row * 256 + off) = pl;
  }
}

// 512-thread (k2) variant: row = t>>3, part = t&7, 16 cols/thread.
__device__ __forceinline__ void ln_sum4(const f32x4 v[4], float* red, int t) {
  float s = 0.f, ss = 0.f;
#pragma unroll
  for (int j = 0; j < 4; ++j)
#pragma unroll
    for (int e = 0; e < 4; ++e) { float x = v[j][e]; s += x; ss += x * x; }
  red[t * 2 + 0] = s;
  red[t * 2 + 1] = ss;
}

__device__ __forceinline__ void ln_build4(const f32x4 v[4],
                                          const f32x4* gp, const f32x4* bp,
                                          float mean, float rstd,
                                          char* Ah, char* Al, int row, int part) {
  const int swz = (row & 7) << 4;
#pragma unroll
  for (int cc = 0; cc < 2; ++cc) {
    u16x8 ph, pl;
#pragma unroll
    for (int e = 0; e < 8; ++e) {
      int j = cc * 2 + (e >> 2), ee = e & 3;
      float x = (v[j][ee] - mean) * rstd * gp[j][ee] + bp[j][ee];
      unsigned short h = f2b(x);
      ph[e] = h;
      pl[e] = f2b(x - b2f(h));
    }
    int off = ((part * 2 + cc) * 16) ^ swz;
    *(u16x8*)(Ah + row * 256 + off) = ph;
    *(u16x8*)(Al + row * 256 + off) = pl;
  }
}

// ---------------- pass 1: MFMA (gb,b) + column-sum reduction ----------------
__global__ __launch_bounds__(256) void k1(
    const float* __restrict__ z,
    const float* __restrict__ lng, const float* __restrict__ lnb,
    const float* __restrict__ bgb, const float* __restrict__ bbv,
    const unsigned short* __restrict__ wT,
    float* __restrict__ partials)
{
  __shared__ __align__(16) char smem[ARENA1_BYTES];
  float* zl  = (float*)smem;                   // merge only (aliases Ah)
  char*  Ah  = smem;
  char*  Al  = smem + 16384;
  float* red = (float*)(smem + RED1_OFF);

  const int t = threadIdx.x;
  const int l = t & 63, wv = t >> 6;
  const int c15 = l & 15, kg = l >> 4;
  const int col0 = wv * 32 + c15;
  const int row = t >> 2, part = t & 3;        // LN mapping
  const int fl8 = l * 8;                        // fragment lane offset
  const int wv2 = wv * 2;

  const unsigned short* wgh = wT + 2 * 16384;
  const unsigned short* wlh = wT + 3 * 16384;
  const unsigned short* wgl = wT + 98304 + 2 * 16384;
  const unsigned short* wll = wT + 98304 + 3 * 16384;
  const float vgb0 = bgb[col0], vgb1 = bgb[col0 + 16];
  const float vlb0 = bbv[col0], vlb1 = bbv[col0 + 16];
  const f32x4* gp = (const f32x4*)(lng + part * 32);
  const f32x4* bp = (const f32x4*)(lnb + part * 32);

  f32x4 breg[4][2];
#pragma unroll
  for (int mt = 0; mt < 4; ++mt)
#pragma unroll
    for (int nt = 0; nt < 2; ++nt) breg[mt][nt] = (f32x4)(0.0f);

  for (int it = 0; it < 8; ++it) {
    const long base = (long)(blockIdx.x * 8 + it) * 64;

    // ---- fused LN(z): global load -> red partials -> local stats -> tiles
    f32x4 v[8];
    {
      const float* zp = z + (base + row) * 128 + part * 32;
#pragma unroll
      for (int j = 0; j < 8; ++j) v[j] = ((const f32x4*)zp)[j];
      ln_sum(v, red, t);
    }
    __syncthreads();   // red visible; prev iter's tile reads complete
    float mean, rstd;
    ln_stats_lds<4>(red, row, mean, rstd);
    ln_build(v, gp, bp, mean, rstd, Ah, Al, row, part);
    __syncthreads();   // tiles visible; red reads done before next overwrite

    // ---- split GEMM (gb,b): coalesced fragment loads ----
    f32x4 ag[4][2], al_[4][2];
#pragma unroll
    for (int mt = 0; mt < 4; ++mt)
#pragma unroll
      for (int nt = 0; nt < 2; ++nt) { ag[mt][nt] = (f32x4)(0.0f); al_[mt][nt] = (f32x4)(0.0f); }
#pragma unroll
    for (int kk = 0; kk < 4; ++kk) {
      s16x8 ah[4], alo[4];
#pragma unroll
      for (int mt = 0; mt < 4; ++mt) {
        int ar = mt * 16 + c15;
        int off = ar * 256 + ((kk * 64 + kg * 16) ^ ((ar & 7) << 4));
        ah[mt]  = __builtin_bit_cast(s16x8, *(const u16x8*)(Ah + off));
        alo[mt] = __builtin_bit_cast(s16x8, *(const u16x8*)(Al + off));
      }
#pragma unroll
      for (int nt = 0; nt < 2; ++nt) {
        int bofs = ((wv2 + nt) * 4 + kk) * 512 + fl8;
        LOADB(bgh, wgh + bofs);
        LOADB(bgl, wgl + bofs);
        LOADB(blh, wlh + bofs);
        LOADB(bll, wll + bofs);
#pragma unroll
        for (int mt = 0; mt < 4; ++mt) {
          ag[mt][nt]  = MFMAB(ah[mt],  bgh, ag[mt][nt]);
          ag[mt][nt]  = MFMAB(alo[mt], bgh, ag[mt][nt]);
          ag[mt][nt]  = MFMAB(ah[mt],  bgl, ag[mt][nt]);
          al_[mt][nt] = MFMAB(ah[mt],  blh, al_[mt][nt]);
          al_[mt][nt] = MFMAB(alo[mt], blh, al_[mt][nt]);
          al_[mt][nt] = MFMAB(ah[mt],  bll, al_[mt][nt]);
        }
      }
    }
#pragma unroll
    for (int nt = 0; nt < 2; ++nt) {
      float vg = nt ? vgb1 : vgb0, vl = nt ? vlb1 : vlb0;
#pragma unroll
      for (int mt = 0; mt < 4; ++mt)
#pragma unroll
        for (int r = 0; r < 4; ++r)
          breg[mt][nt][r] += sigm(ag[mt][nt][r] + vg) * (al_[mt][nt][r] + vl);
    }
  }

  __syncthreads();   // all tile reads done; arena reusable as f32 merge buf
  float* sm = zl;
#pragma unroll
  for (int mt = 0; mt < 2; ++mt)
#pragma unroll
    for (int nt = 0; nt < 2; ++nt) {
      int col = col0 + nt * 16;
#pragma unroll
      for (int r = 0; r < 4; ++r) {
        int krow = mt * 16 + kg * 4 + r;
        sm[krow * 128 + col] = breg[mt][nt][r] + breg[mt + 2][nt][r];
      }
    }
  __syncthreads();
  for (int i = 0; i < 16; ++i) {
    int e = i * 256 + t;
    partials[(long)blockIdx.x * 4096 + e] = sm[e];
  }
}

// ---------------- reductions (r5 verbatim) ----------------------------------
__global__ void k_red_a(const float* __restrict__ pin, double* __restrict__ pout) {
  int gid = blockIdx.x * 256 + threadIdx.x;
  int e = gid & 4095, chunk = gid >> 12;
  const float* p = pin + (long)chunk * 16 * 4096 + e;
  double a0 = 0, a1 = 0, a2 = 0, a3 = 0;
#pragma unroll
  for (int i = 0; i < 16; i += 4) {
    a0 += (double)p[(i + 0) * 4096]; a1 += (double)p[(i + 1) * 4096];
    a2 += (double)p[(i + 2) * 4096]; a3 += (double)p[(i + 3) * 4096];
  }
  pout[gid] = (a0 + a1) + (a2 + a3);
}

__global__ void k_red_b(const double* __restrict__ pin, float* __restrict__ sfin) {
  int e = blockIdx.x * 256 + threadIdx.x;
  double a0 = 0, a1 = 0, a2 = 0, a3 = 0;
#pragma unroll
  for (int i = 0; i < 64; i += 4) {
    a0 += pin[(i + 0) * 4096 + e]; a1 += pin[(i + 1) * 4096 + e];
    a2 += pin[(i + 2) * 4096 + e]; a3 += pin[(i + 3) * 4096 + e];
  }
  sfin[e] = (float)((a0 + a1) + (a2 + a3));
}

// ---------------- pass 2: 512 threads, 8 waves, 64x16 slice per wave --------
__global__ __launch_bounds__(512, 4) void k2(
    const float* __restrict__ z,
    const float* __restrict__ lnig, const float* __restrict__ lnib,
    const float* __restrict__ bga, const float* __restrict__ ba,
    const float* __restrict__ bgo,
    const float* __restrict__ lnog, const float* __restrict__ lnob,
    const float* __restrict__ bo,
    const unsigned short* __restrict__ wT,
    const float* __restrict__ sfin,
    float* __restrict__ out)
{
  __shared__ __align__(16) char smem[ARENA2_BYTES];
  float* zl  = (float*)smem;
  char*  Ah  = smem;
  char*  Al  = smem + 16384;
  float* red = (float*)(smem + RED2_OFF);

  const int t = threadIdx.x;
  const int l = t & 63, w = t >> 6;            // wave id in [0,8)
  const int c15 = l & 15, kg = l >> 4;
  const int col0 = w * 16 + c15;               // wave w owns cols [w*16, w*16+16)
  const int row = t >> 3, part = t & 7;        // LN mapping (16 cols/thread)
  const int fl8 = l * 8;
  const long base = (long)blockIdx.x * 64;

  // ---- phase 1: fused LN(z) -> tiles ----
  {
    f32x4 v[4];
    const float* zp = z + (base + row) * 128 + part * 16;
#pragma unroll
    for (int j = 0; j < 4; ++j) v[j] = ((const f32x4*)zp)[j];
    ln_sum4(v, red, t);
    __syncthreads();   // B1a: red visible
    float mean, rstd;
    ln_stats_lds<8>(red, row, mean, rstd);
    ln_build4(v, (const f32x4*)(lnig + part * 16), (const f32x4*)(lnib + part * 16),
              mean, rstd, Ah, Al, row, part);
  }
  __syncthreads();   // B1: tiles visible

  // ---- phase 2: GEMM pass A (ga, a) ----
  f32x4 ag[4];
  {
    const unsigned short* wgah = wT + 0 * 16384;
    const unsigned short* wah  = wT + 1 * 16384;
    const unsigned short* wgal = wT + 98304 + 0 * 16384;
    const unsigned short* wal  = wT + 98304 + 1 * 16384;
    f32x4 g_[4], a_[4];
#pragma unroll
    for (int mt = 0; mt < 4; ++mt) { g_[mt] = (f32x4)(0.0f); a_[mt] = (f32x4)(0.0f); }
#pragma unroll
    for (int kk = 0; kk < 4; ++kk) {
      s16x8 ah[4], alo[4];
#pragma unroll
      for (int mt = 0; mt < 4; ++mt) {
        int ar = mt * 16 + c15;
        int off = ar * 256 + ((kk * 64 + kg * 16) ^ ((ar & 7) << 4));
        ah[mt]  = __builtin_bit_cast(s16x8, *(const u16x8*)(Ah + off));
        alo[mt] = __builtin_bit_cast(s16x8, *(const u16x8*)(Al + off));
      }
      int bofs = (w * 4 + kk) * 512 + fl8;
      LOADB(g_h, wgah + bofs);
      LOADB(g_l, wgal + bofs);
      LOADB(a_h, wah + bofs);
      LOADB(a_l, wal + bofs);
#pragma unroll
      for (int mt = 0; mt < 4; ++mt) {
        g_[mt] = MFMAB(ah[mt],  g_h, g_[mt]);
        g_[mt] = MFMAB(alo[mt], g_h, g_[mt]);
        g_[mt] = MFMAB(ah[mt],  g_l, g_[mt]);
        a_[mt] = MFMAB(ah[mt],  a_h, a_[mt]);
        a_[mt] = MFMAB(alo[mt], a_h, a_[mt]);
        a_[mt] = MFMAB(ah[mt],  a_l, a_[mt]);
      }
    }
    float vga = bga[col0], vba = ba[col0];
#pragma unroll
    for (int mt = 0; mt < 4; ++mt)
#pragma unroll
      for (int r = 0; r < 4; ++r)
        ag[mt][r] = sigm(g_[mt][r] + vga) * (a_[mt][r] + vba);
  }

  // ---- phase 3: GEMM pass B: go ----
  f32x4 gg[4];
#pragma unroll
  for (int mt = 0; mt < 4; ++mt) gg[mt] = (f32x4)(0.0f);
  {
    const unsigned short* wgoh = wT + 4 * 16384;
    const unsigned short* wgol = wT + 98304 + 4 * 16384;
#pragma unroll
    for (int kk = 0; kk < 4; ++kk) {
      s16x8 ah[4], alo[4];
#pragma unroll
      for (int mt = 0; mt < 4; ++mt) {
        int ar = mt * 16 + c15;
        int off = ar * 256 + ((kk * 64 + kg * 16) ^ ((ar & 7) << 4));
        ah[mt]  = __builtin_bit_cast(s16x8, *(const u16x8*)(Ah + off));
        alo[mt] = __builtin_bit_cast(s16x8, *(const u16x8*)(Al + off));
      }
      int bofs = (w * 4 + kk) * 512 + fl8;
      LOADB(o_h, wgoh + bofs);
      LOADB(o_l, wgol + bofs);
#pragma unroll
      for (int mt = 0; mt < 4; ++mt) {
        gg[mt] = MFMAB(ah[mt],  o_h, gg[mt]);
        gg[mt] = MFMAB(alo[mt], o_h, gg[mt]);
        gg[mt] = MFMAB(ah[mt],  o_l, gg[mt]);
      }
    }
  }
  {
    float vgo = bgo[col0];
#pragma unroll
    for (int mt = 0; mt < 4; ++mt)
#pragma unroll
      for (int r = 0; r < 4; ++r)
        gg[mt][r] = sigm(gg[mt][r] + vgo);
  }
  __syncthreads();   // B2: all tile reads done; arena reusable as f32 zl

  // ---- phase 4: kv = a * s[k] -> zl ----
#pragma unroll
  for (int mt = 0; mt < 4; ++mt)
#pragma unroll
    for (int r = 0; r < 4; ++r) {
      int rw = mt * 16 + kg * 4 + r;
      zl[rw * ZL_STRIDE + col0] = ag[mt][r] * sfin[(rw & 31) * 128 + col0];
    }
  __syncthreads();   // B3: kv visible

  // ---- phase 5: fused LN(kv) -> tiles ----
  {
    f32x4 v[4];
    const f32x4* kp = (const f32x4*)(zl + row * ZL_STRIDE + part * 16);
#pragma unroll
    for (int j = 0; j < 4; ++j) v[j] = kp[j];
    ln_sum4(v, red, t);
    __syncthreads();   // B4a: red visible AND all kv (zl) reads complete
    float mean, rstd;
    ln_stats_lds<8>(red, row, mean, rstd);
    // build writes Ah/Al (alias zl) — safe: no zl reads after B4a; red is
    // a disjoint region so concurrent red reads don't alias these writes.
    ln_build4(v, (const f32x4*)(lnog + part * 16), (const f32x4*)(lnob + part * 16),
              mean, rstd, Ah, Al, row, part);
  }
  __syncthreads();   // B5: tiles visible

  // ---- phase 6: w_o GEMM ----
  f32x4 acc[4];
#pragma unroll
  for (int mt = 0; mt < 4; ++mt) acc[mt] = (f32x4)(0.0f);
  {
    const unsigned short* woh = wT + 5 * 16384;
    const unsigned short* wol = wT + 98304 + 5 * 16384;
#pragma unroll
    for (int kk = 0; kk < 4; ++kk) {
      s16x8 ah[4], alo[4];
#pragma unroll
      for (int mt = 0; mt < 4; ++mt) {
        int ar = mt * 16 + c15;
        int off = ar * 256 + ((kk * 64 + kg * 16) ^ ((ar & 7) << 4));
        ah[mt]  = __builtin_bit_cast(s16x8, *(const u16x8*)(Ah + off));
        alo[mt] = __builtin_bit_cast(s16x8, *(const u16x8*)(Al + off));
      }
      int bofs = (w * 4 + kk) * 512 + fl8;
      LOADB(o_h, woh + bofs);
      LOADB(o_l, wol + bofs);
#pragma unroll
      for (int mt = 0; mt < 4; ++mt) {
        acc[mt] = MFMAB(ah[mt],  o_h, acc[mt]);
        acc[mt] = MFMAB(alo[mt], o_h, acc[mt]);
        acc[mt] = MFMAB(ah[mt],  o_l, acc[mt]);
      }
    }
  }

  // ---- phase 7: out = sigm(go) * (acc + b_o) ----
  {
    float bov = bo[col0];
#pragma unroll
    for (int mt = 0; mt < 4; ++mt)
#pragma unroll
      for (int r = 0; r < 4; ++r) {
        int rw = mt * 16 + kg * 4 + r;
        out[(base + rw) * 128 + col0] = gg[mt][r] * (acc[mt][r] + bov);
      }
  }
}

// ---------------------------------------------------------------------------
extern "C" void kernel_launch(void* const* d_in, const int* in_sizes, int n_in,
                              void* d_out, int out_size, void* d_ws, size_t ws_size,
                              hipStream_t stream) {
  const float* z    = (const float*)d_in[0];
  const float* lnig = (const float*)d_in[1];
  const float* lnib = (const float*)d_in[2];
  const float* w_a  = (const float*)d_in[3];
  const float* b_a  = (const float*)d_in[4];
  const float* w_ga = (const float*)d_in[5];
  const float* b_ga = (const float*)d_in[6];
  const float* w_b  = (const float*)d_in[7];
  const float* b_b  = (const float*)d_in[8];
  const float* w_gb = (const float*)d_in[9];
  const float* b_gb = (const float*)d_in[10];
  const float* lnog = (const float*)d_in[11];
  const float* lnob = (const float*)d_in[12];
  const float* w_go = (const float*)d_in[13];
  const float* b_go = (const float*)d_in[14];
  const float* w_o  = (const float*)d_in[15];
  const float* b_o  = (const float*)d_in[16];

  // ws: sfin 16KB @0, wP 384KB @16384
  float* sfin = (float*)d_ws;
  unsigned short* wT = (unsigned short*)((char*)d_ws + 16384);

  // big scratch in d_out (fully overwritten by k2):
  float*  partials  = (float*)d_out;                        // 16 MB
  double* partials2 = (double*)((char*)d_out + 16777216);   //  2 MB

  k_pack<<<384, 256, 0, stream>>>(w_ga, w_a, w_gb, w_b, w_go, w_o, wT);
  k1<<<1024, 256, 0, stream>>>(z, lnig, lnib, b_gb, b_b, wT, partials);
  k_red_a<<<1024, 256, 0, stream>>>(partials, partials2);
  k_red_b<<<16, 256, 0, stream>>>(partials2, sfin);
  k2<<<8192, 512, 0, stream>>>(z, lnig, lnib,
                               b_ga, b_a, b_go, lnog, lnob, b_o,
                               wT, sfin, (float*)d_out);
}

// Round 7
// 422.831 us; speedup vs baseline: 1.2339x; 1.0869x over previous
//
#include <hip/hip_runtime.h>
#include <stdint.h>

// ---------------------------------------------------------------------------
// Round 18: instruction-count reduction (k2 is ~82% issue-occupied).
//   - GATE GEMMs (ga, gb, go) drop to pure-hi 1-MFMA: gate error passes
//     through sigmoid (slope<=1/4) -> end-to-end absmax impact ~+0.005,
//     well inside the 0.086 threshold (current 0.0156). LINEAR paths
//     (a, b) and final w_o keep the full 3-term split (the 16K-row b-sum
//     accumulation path is untouched).
//   - k2 phases 2+3 FUSED into one kk loop (same A-tiles): -32
//     ds_read_b128/wave, better MFMA ILP. Peak live regs ~110 < 128 bin.
//   - k1: same gate-drop (6->4 MFMA per mt/nt/kk; gb-lo loads gone).
//   - Everything else r17 verbatim.
// ---------------------------------------------------------------------------

typedef __attribute__((ext_vector_type(8))) short          s16x8;
typedef __attribute__((ext_vector_type(8))) unsigned short u16x8;
typedef __attribute__((ext_vector_type(4))) float          f32x4;

#define MFMAB(A, B, C) __builtin_amdgcn_mfma_f32_16x16x32_bf16((A), (B), (C), 0, 0, 0)

__device__ __forceinline__ unsigned short f2b(float x) {   // f32 -> bf16 RNE (HW cvt)
  return __builtin_bit_cast(unsigned short, (__bf16)x);
}
__device__ __forceinline__ float b2f(unsigned short u) {
  return __builtin_bit_cast(float, (uint32_t)u << 16);
}
__device__ __forceinline__ float sigm(float x) { return 1.0f / (1.0f + __expf(-x)); }

#define LOADB(dst, ptr) s16x8 dst = __builtin_bit_cast(s16x8, *(const u16x8*)(ptr))

#define ZL_STRIDE 132   // floats per LDS row (16B-aligned rows)

// k1 arena (34816 B): tiles Ah @0 / Al @16384 (zl merge aliases Ah);
// red @32768 (256 thr * 8 B).
#define ARENA1_BYTES 34816
#define RED1_OFF     32768
// k2 arena (37888 B): zl f32[64][132] @0; Ah @0, Al @16384 (alias zl);
// red @33792 (512 thr * 8 B).
#define ARENA2_BYTES 37888
#define RED2_OFF     33792

// ---------------- weight pack: fragment-ordered -----------------------------
// hi: wP[mat*16384 + cb*2048 + kk*512 + l*8 + e]; lo at +98304.
// value = src[(kk*32 + (l>>4)*8 + e)*128 + cb*16 + (l&15)]
// mats: 0=ga 1=a 2=gb 3=b 4=go 5=o
__global__ void k_pack(const float* __restrict__ wga, const float* __restrict__ wa,
                       const float* __restrict__ wgb, const float* __restrict__ wb,
                       const float* __restrict__ wgo, const float* __restrict__ wo,
                       unsigned short* __restrict__ wP) {
  int gid = blockIdx.x * 256 + threadIdx.x;      // 6*16384 = 98304
  int mat = gid >> 14, idx = gid & 16383;
  int cb = idx >> 11;
  int kk = (idx >> 9) & 3;
  int l  = (idx >> 3) & 63;
  int e  = idx & 7;
  int col = cb * 16 + (l & 15);
  int k   = kk * 32 + (l >> 4) * 8 + e;
  const float* src = (mat == 0) ? wga : (mat == 1) ? wa : (mat == 2) ? wgb
                   : (mat == 3) ? wb  : (mat == 4) ? wgo : wo;
  float v = src[k * 128 + col];
  unsigned short h = f2b(v);
  wP[gid]         = h;
  wP[98304 + gid] = f2b(v - b2f(h));
}

// ---------------- fused-LN helpers ------------------------------------------
// Parallel stats: each thread reads its row's GRP partials in ascending part
// order — identical values & FP order as a serial gather (bit-exact),
// computed redundantly by all threads of the row (deterministic).
template<int GRP>
__device__ __forceinline__ void ln_stats_lds(const float* red, int row,
                                             float& mean, float& rstd) {
  float S = 0.f, SS = 0.f;
#pragma unroll
  for (int p = 0; p < GRP; ++p) {
    S  += red[(row * GRP + p) * 2 + 0];
    SS += red[(row * GRP + p) * 2 + 1];
  }
  mean = S * (1.0f / 128.0f);
  const float var = SS * (1.0f / 128.0f) - mean * mean;
  rstd = rsqrtf(var + 1e-5f);
}

// 256-thread (k1) variant: row = t>>2, part = t&3, 32 cols/thread.
__device__ __forceinline__ void ln_sum(const f32x4 v[8], float* red, int t) {
  float s = 0.f, ss = 0.f;
#pragma unroll
  for (int j = 0; j < 8; ++j)
#pragma unroll
    for (int e = 0; e < 4; ++e) { float x = v[j][e]; s += x; ss += x * x; }
  red[t * 2 + 0] = s;
  red[t * 2 + 1] = ss;
}

__device__ __forceinline__ void ln_build(const f32x4 v[8],
                                         const f32x4* gp, const f32x4* bp,
                                         float mean, float rstd,
                                         char* Ah, char* Al, int row, int part) {
  const int swz = (row & 7) << 4;
#pragma unroll
  for (int cc = 0; cc < 4; ++cc) {
    u16x8 ph, pl;
#pragma unroll
    for (int e = 0; e < 8; ++e) {
      int j = cc * 2 + (e >> 2), ee = e & 3;
      float x = (v[j][ee] - mean) * rstd * gp[j][ee] + bp[j][ee];
      unsigned short h = f2b(x);
      ph[e] = h;
      pl[e] = f2b(x - b2f(h));
    }
    int off = ((part * 4 + cc) * 16) ^ swz;
    *(u16x8*)(Ah + row * 256 + off) = ph;
    *(u16x8*)(Al + row * 256 + off) = pl;
  }
}

// 512-thread (k2) variant: row = t>>3, part = t&7, 16 cols/thread.
__device__ __forceinline__ void ln_sum4(const f32x4 v[4], float* red, int t) {
  float s = 0.f, ss = 0.f;
#pragma unroll
  for (int j = 0; j < 4; ++j)
#pragma unroll
    for (int e = 0; e < 4; ++e) { float x = v[j][e]; s += x; ss += x * x; }
  red[t * 2 + 0] = s;
  red[t * 2 + 1] = ss;
}

__device__ __forceinline__ void ln_build4(const f32x4 v[4],
                                          const f32x4* gp, const f32x4* bp,
                                          float mean, float rstd,
                                          char* Ah, char* Al, int row, int part) {
  const int swz = (row & 7) << 4;
#pragma unroll
  for (int cc = 0; cc < 2; ++cc) {
    u16x8 ph, pl;
#pragma unroll
    for (int e = 0; e < 8; ++e) {
      int j = cc * 2 + (e >> 2), ee = e & 3;
      float x = (v[j][ee] - mean) * rstd * gp[j][ee] + bp[j][ee];
      unsigned short h = f2b(x);
      ph[e] = h;
      pl[e] = f2b(x - b2f(h));
    }
    int off = ((part * 2 + cc) * 16) ^ swz;
    *(u16x8*)(Ah + row * 256 + off) = ph;
    *(u16x8*)(Al + row * 256 + off) = pl;
  }
}

// ---------------- pass 1: MFMA (gb,b) + column-sum reduction ----------------
__global__ __launch_bounds__(256) void k1(
    const float* __restrict__ z,
    const float* __restrict__ lng, const float* __restrict__ lnb,
    const float* __restrict__ bgb, const float* __restrict__ bbv,
    const unsigned short* __restrict__ wT,
    float* __restrict__ partials)
{
  __shared__ __align__(16) char smem[ARENA1_BYTES];
  float* zl  = (float*)smem;                   // merge only (aliases Ah)
  char*  Ah  = smem;
  char*  Al  = smem + 16384;
  float* red = (float*)(smem + RED1_OFF);

  const int t = threadIdx.x;
  const int l = t & 63, wv = t >> 6;
  const int c15 = l & 15, kg = l >> 4;
  const int col0 = wv * 32 + c15;
  const int row = t >> 2, part = t & 3;        // LN mapping
  const int fl8 = l * 8;                        // fragment lane offset
  const int wv2 = wv * 2;

  const unsigned short* wgh = wT + 2 * 16384;            // gb hi (gate: hi only)
  const unsigned short* wlh = wT + 3 * 16384;            // b  hi
  const unsigned short* wll = wT + 98304 + 3 * 16384;    // b  lo
  const float vgb0 = bgb[col0], vgb1 = bgb[col0 + 16];
  const float vlb0 = bbv[col0], vlb1 = bbv[col0 + 16];
  const f32x4* gp = (const f32x4*)(lng + part * 32);
  const f32x4* bp = (const f32x4*)(lnb + part * 32);

  f32x4 breg[4][2];
#pragma unroll
  for (int mt = 0; mt < 4; ++mt)
#pragma unroll
    for (int nt = 0; nt < 2; ++nt) breg[mt][nt] = (f32x4)(0.0f);

  for (int it = 0; it < 8; ++it) {
    const long base = (long)(blockIdx.x * 8 + it) * 64;

    // ---- fused LN(z): global load -> red partials -> local stats -> tiles
    f32x4 v[8];
    {
      const float* zp = z + (base + row) * 128 + part * 32;
#pragma unroll
      for (int j = 0; j < 8; ++j) v[j] = ((const f32x4*)zp)[j];
      ln_sum(v, red, t);
    }
    __syncthreads();   // red visible; prev iter's tile reads complete
    float mean, rstd;
    ln_stats_lds<4>(red, row, mean, rstd);
    ln_build(v, gp, bp, mean, rstd, Ah, Al, row, part);
    __syncthreads();   // tiles visible; red reads done before next overwrite

    // ---- split GEMM (gb gate 1-term, b linear 3-term) ----
    f32x4 ag[4][2], al_[4][2];
#pragma unroll
    for (int mt = 0; mt < 4; ++mt)
#pragma unroll
      for (int nt = 0; nt < 2; ++nt) { ag[mt][nt] = (f32x4)(0.0f); al_[mt][nt] = (f32x4)(0.0f); }
#pragma unroll
    for (int kk = 0; kk < 4; ++kk) {
      s16x8 ah[4], alo[4];
#pragma unroll
      for (int mt = 0; mt < 4; ++mt) {
        int ar = mt * 16 + c15;
        int off = ar * 256 + ((kk * 64 + kg * 16) ^ ((ar & 7) << 4));
        ah[mt]  = __builtin_bit_cast(s16x8, *(const u16x8*)(Ah + off));
        alo[mt] = __builtin_bit_cast(s16x8, *(const u16x8*)(Al + off));
      }
#pragma unroll
      for (int nt = 0; nt < 2; ++nt) {
        int bofs = ((wv2 + nt) * 4 + kk) * 512 + fl8;
        LOADB(bgh, wgh + bofs);
        LOADB(blh, wlh + bofs);
        LOADB(bll, wll + bofs);
#pragma unroll
        for (int mt = 0; mt < 4; ++mt) {
          ag[mt][nt]  = MFMAB(ah[mt],  bgh, ag[mt][nt]);
          al_[mt][nt] = MFMAB(ah[mt],  blh, al_[mt][nt]);
          al_[mt][nt] = MFMAB(alo[mt], blh, al_[mt][nt]);
          al_[mt][nt] = MFMAB(ah[mt],  bll, al_[mt][nt]);
        }
      }
    }
#pragma unroll
    for (int nt = 0; nt < 2; ++nt) {
      float vg = nt ? vgb1 : vgb0, vl = nt ? vlb1 : vlb0;
#pragma unroll
      for (int mt = 0; mt < 4; ++mt)
#pragma unroll
        for (int r = 0; r < 4; ++r)
          breg[mt][nt][r] += sigm(ag[mt][nt][r] + vg) * (al_[mt][nt][r] + vl);
    }
  }

  __syncthreads();   // all tile reads done; arena reusable as f32 merge buf
  float* sm = zl;
#pragma unroll
  for (int mt = 0; mt < 2; ++mt)
#pragma unroll
    for (int nt = 0; nt < 2; ++nt) {
      int col = col0 + nt * 16;
#pragma unroll
      for (int r = 0; r < 4; ++r) {
        int krow = mt * 16 + kg * 4 + r;
        sm[krow * 128 + col] = breg[mt][nt][r] + breg[mt + 2][nt][r];
      }
    }
  __syncthreads();
  for (int i = 0; i < 16; ++i) {
    int e = i * 256 + t;
    partials[(long)blockIdx.x * 4096 + e] = sm[e];
  }
}

// ---------------- reductions (r5 verbatim) ----------------------------------
__global__ void k_red_a(const float* __restrict__ pin, double* __restrict__ pout) {
  int gid = blockIdx.x * 256 + threadIdx.x;
  int e = gid & 4095, chunk = gid >> 12;
  const float* p = pin + (long)chunk * 16 * 4096 + e;
  double a0 = 0, a1 = 0, a2 = 0, a3 = 0;
#pragma unroll
  for (int i = 0; i < 16; i += 4) {
    a0 += (double)p[(i + 0) * 4096]; a1 += (double)p[(i + 1) * 4096];
    a2 += (double)p[(i + 2) * 4096]; a3 += (double)p[(i + 3) * 4096];
  }
  pout[gid] = (a0 + a1) + (a2 + a3);
}

__global__ void k_red_b(const double* __restrict__ pin, float* __restrict__ sfin) {
  int e = blockIdx.x * 256 + threadIdx.x;
  double a0 = 0, a1 = 0, a2 = 0, a3 = 0;
#pragma unroll
  for (int i = 0; i < 64; i += 4) {
    a0 += pin[(i + 0) * 4096 + e]; a1 += pin[(i + 1) * 4096 + e];
    a2 += pin[(i + 2) * 4096 + e]; a3 += pin[(i + 3) * 4096 + e];
  }
  sfin[e] = (float)((a0 + a1) + (a2 + a3));
}

// ---------------- pass 2: 512 threads, 8 waves, 64x16 slice per wave --------
__global__ __launch_bounds__(512, 4) void k2(
    const float* __restrict__ z,
    const float* __restrict__ lnig, const float* __restrict__ lnib,
    const float* __restrict__ bga, const float* __restrict__ ba,
    const float* __restrict__ bgo,
    const float* __restrict__ lnog, const float* __restrict__ lnob,
    const float* __restrict__ bo,
    const unsigned short* __restrict__ wT,
    const float* __restrict__ sfin,
    float* __restrict__ out)
{
  __shared__ __align__(16) char smem[ARENA2_BYTES];
  float* zl  = (float*)smem;
  char*  Ah  = smem;
  char*  Al  = smem + 16384;
  float* red = (float*)(smem + RED2_OFF);

  const int t = threadIdx.x;
  const int l = t & 63, w = t >> 6;            // wave id in [0,8)
  const int c15 = l & 15, kg = l >> 4;
  const int col0 = w * 16 + c15;               // wave w owns cols [w*16, w*16+16)
  const int row = t >> 3, part = t & 7;        // LN mapping (16 cols/thread)
  const int fl8 = l * 8;
  const long base = (long)blockIdx.x * 64;

  // ---- phase 1: fused LN(z) -> tiles ----
  {
    f32x4 v[4];
    const float* zp = z + (base + row) * 128 + part * 16;
#pragma unroll
    for (int j = 0; j < 4; ++j) v[j] = ((const f32x4*)zp)[j];
    ln_sum4(v, red, t);
    __syncthreads();   // B1a: red visible
    float mean, rstd;
    ln_stats_lds<8>(red, row, mean, rstd);
    ln_build4(v, (const f32x4*)(lnig + part * 16), (const f32x4*)(lnib + part * 16),
              mean, rstd, Ah, Al, row, part);
  }
  __syncthreads();   // B1: tiles visible

  // ---- phase 2+3 FUSED: ga (gate, 1-term), a (linear, 3-term),
  //      go (gate, 1-term) share A-fragment reads ----
  f32x4 ag[4], gg[4];
  {
    const unsigned short* wgah = wT + 0 * 16384;           // ga hi
    const unsigned short* wah  = wT + 1 * 16384;           // a  hi
    const unsigned short* wal  = wT + 98304 + 1 * 16384;   // a  lo
    const unsigned short* wgoh = wT + 4 * 16384;           // go hi
    f32x4 g_[4], a_[4];
#pragma unroll
    for (int mt = 0; mt < 4; ++mt) {
      g_[mt] = (f32x4)(0.0f); a_[mt] = (f32x4)(0.0f); gg[mt] = (f32x4)(0.0f);
    }
#pragma unroll
    for (int kk = 0; kk < 4; ++kk) {
      s16x8 ah[4], alo[4];
#pragma unroll
      for (int mt = 0; mt < 4; ++mt) {
        int ar = mt * 16 + c15;
        int off = ar * 256 + ((kk * 64 + kg * 16) ^ ((ar & 7) << 4));
        ah[mt]  = __builtin_bit_cast(s16x8, *(const u16x8*)(Ah + off));
        alo[mt] = __builtin_bit_cast(s16x8, *(const u16x8*)(Al + off));
      }
      int bofs = (w * 4 + kk) * 512 + fl8;
      LOADB(g_h, wgah + bofs);
      LOADB(a_h, wah + bofs);
      LOADB(a_l, wal + bofs);
      LOADB(o_h, wgoh + bofs);
#pragma unroll
      for (int mt = 0; mt < 4; ++mt) {
        g_[mt] = MFMAB(ah[mt],  g_h, g_[mt]);
        a_[mt] = MFMAB(ah[mt],  a_h, a_[mt]);
        a_[mt] = MFMAB(alo[mt], a_h, a_[mt]);
        a_[mt] = MFMAB(ah[mt],  a_l, a_[mt]);
        gg[mt] = MFMAB(ah[mt],  o_h, gg[mt]);
      }
    }
    float vga = bga[col0], vba = ba[col0], vgo = bgo[col0];
#pragma unroll
    for (int mt = 0; mt < 4; ++mt)
#pragma unroll
      for (int r = 0; r < 4; ++r) {
        ag[mt][r] = sigm(g_[mt][r] + vga) * (a_[mt][r] + vba);
        gg[mt][r] = sigm(gg[mt][r] + vgo);
      }
  }
  __syncthreads();   // B2: all tile reads done; arena reusable as f32 zl

  // ---- phase 4: kv = a * s[k] -> zl ----
#pragma unroll
  for (int mt = 0; mt < 4; ++mt)
#pragma unroll
    for (int r = 0; r < 4; ++r) {
      int rw = mt * 16 + kg * 4 + r;
      zl[rw * ZL_STRIDE + col0] = ag[mt][r] * sfin[(rw & 31) * 128 + col0];
    }
  __syncthreads();   // B3: kv visible

  // ---- phase 5: fused LN(kv) -> tiles ----
  {
    f32x4 v[4];
    const f32x4* kp = (const f32x4*)(zl + row * ZL_STRIDE + part * 16);
#pragma unroll
    for (int j = 0; j < 4; ++j) v[j] = kp[j];
    ln_sum4(v, red, t);
    __syncthreads();   // B4a: red visible AND all kv (zl) reads complete
    float mean, rstd;
    ln_stats_lds<8>(red, row, mean, rstd);
    // build writes Ah/Al (alias zl) — safe: no zl reads after B4a; red is
    // a disjoint region so concurrent red reads don't alias these writes.
    ln_build4(v, (const f32x4*)(lnog + part * 16), (const f32x4*)(lnob + part * 16),
              mean, rstd, Ah, Al, row, part);
  }
  __syncthreads();   // B5: tiles visible

  // ---- phase 6: w_o GEMM (full 3-term) ----
  f32x4 acc[4];
#pragma unroll
  for (int mt = 0; mt < 4; ++mt) acc[mt] = (f32x4)(0.0f);
  {
    const unsigned short* woh = wT + 5 * 16384;
    const unsigned short* wol = wT + 98304 + 5 * 16384;
#pragma unroll
    for (int kk = 0; kk < 4; ++kk) {
      s16x8 ah[4], alo[4];
#pragma unroll
      for (int mt = 0; mt < 4; ++mt) {
        int ar = mt * 16 + c15;
        int off = ar * 256 + ((kk * 64 + kg * 16) ^ ((ar & 7) << 4));
        ah[mt]  = __builtin_bit_cast(s16x8, *(const u16x8*)(Ah + off));
        alo[mt] = __builtin_bit_cast(s16x8, *(const u16x8*)(Al + off));
      }
      int bofs = (w * 4 + kk) * 512 + fl8;
      LOADB(o_h, woh + bofs);
      LOADB(o_l, wol + bofs);
#pragma unroll
      for (int mt = 0; mt < 4; ++mt) {
        acc[mt] = MFMAB(ah[mt],  o_h, acc[mt]);
        acc[mt] = MFMAB(alo[mt], o_h, acc[mt]);
        acc[mt] = MFMAB(ah[mt],  o_l, acc[mt]);
      }
    }
  }

  // ---- phase 7: out = sigm(go) * (acc + b_o) ----
  {
    float bov = bo[col0];
#pragma unroll
    for (int mt = 0; mt < 4; ++mt)
#pragma unroll
      for (int r = 0; r < 4; ++r) {
        int rw = mt * 16 + kg * 4 + r;
        out[(base + rw) * 128 + col0] = gg[mt][r] * (acc[mt][r] + bov);
      }
  }
}

// ---------------------------------------------------------------------------
extern "C" void kernel_launch(void* const* d_in, const int* in_sizes, int n_in,
                              void* d_out, int out_size, void* d_ws, size_t ws_size,
                              hipStream_t stream) {
  const float* z    = (const float*)d_in[0];
  const float* lnig = (const float*)d_in[1];
  const float* lnib = (const float*)d_in[2];
  const float* w_a  = (const float*)d_in[3];
  const float* b_a  = (const float*)d_in[4];
  const float* w_ga = (const float*)d_in[5];
  const float* b_ga = (const float*)d_in[6];
  const float* w_b  = (const float*)d_in[7];
  const float* b_b  = (const float*)d_in[8];
  const float* w_gb = (const float*)d_in[9];
  const float* b_gb = (const float*)d_in[10];
  const float* lnog = (const float*)d_in[11];
  const float* lnob = (const float*)d_in[12];
  const float* w_go = (const float*)d_in[13];
  const float* b_go = (const float*)d_in[14];
  const float* w_o  = (const float*)d_in[15];
  const float* b_o  = (const float*)d_in[16];

  // ws: sfin 16KB @0, wP 384KB @16384
  float* sfin = (float*)d_ws;
  unsigned short* wT = (unsigned short*)((char*)d_ws + 16384);

  // big scratch in d_out (fully overwritten by k2):
  float*  partials  = (float*)d_out;                        // 16 MB
  double* partials2 = (double*)((char*)d_out + 16777216);   //  2 MB

  k_pack<<<384, 256, 0, stream>>>(w_ga, w_a, w_gb, w_b, w_go, w_o, wT);
  k1<<<1024, 256, 0, stream>>>(z, lnig, lnib, b_gb, b_b, wT, partials);
  k_red_a<<<1024, 256, 0, stream>>>(partials, partials2);
  k_red_b<<<16, 256, 0, stream>>>(partials2, sfin);
  k2<<<8192, 512, 0, stream>>>(z, lnig, lnib,
                               b_ga, b_a, b_go, lnog, lnob, b_o,
                               wT, sfin, (float*)d_out);
}

// Round 10
// 421.398 us; speedup vs baseline: 1.2381x; 1.0034x over previous
//
#include <hip/hip_runtime.h>
#include <stdint.h>

// ---------------------------------------------------------------------------
// Round 21: single-variable isolation of r20's failure.
//   Base: r18 VERBATIM (last-known-good, 422.8us, absmax 0.015625) —
//   interleaved red[] layout, serial-ish LDS stats, gate 1-term, fused
//   phases 2+3, 3-term a-path and w_o.
//   ONLY change: kk=0 weight-fragment prefetch (k1: loop-invariant
//   kk0/nt0 frags hoisted out of the it-loop; k2: phase-2+3 frags at
//   kernel top, w_o frags after B2). Value-identical global loads of
//   constant weights.
//   If this fails -> prefetch is the r20 culprit; revert to r18 next.
//   If this passes -> r20's red-split was the defect; abandoned.
// ---------------------------------------------------------------------------

typedef __attribute__((ext_vector_type(8))) short          s16x8;
typedef __attribute__((ext_vector_type(8))) unsigned short u16x8;
typedef __attribute__((ext_vector_type(4))) float          f32x4;

#define MFMAB(A, B, C) __builtin_amdgcn_mfma_f32_16x16x32_bf16((A), (B), (C), 0, 0, 0)

__device__ __forceinline__ unsigned short f2b(float x) {   // f32 -> bf16 RNE (HW cvt)
  return __builtin_bit_cast(unsigned short, (__bf16)x);
}
__device__ __forceinline__ float b2f(unsigned short u) {
  return __builtin_bit_cast(float, (uint32_t)u << 16);
}
__device__ __forceinline__ float sigm(float x) { return 1.0f / (1.0f + __expf(-x)); }

__device__ __forceinline__ s16x8 loadb(const unsigned short* p) {
  return __builtin_bit_cast(s16x8, *(const u16x8*)(p));
}

#define ZL_STRIDE 132   // floats per LDS row (16B-aligned rows)

// k1 arena (34816 B): tiles Ah @0 / Al @16384 (zl merge aliases Ah);
// red @32768 (256 thr * 8 B).
#define ARENA1_BYTES 34816
#define RED1_OFF     32768
// k2 arena (37888 B): zl f32[64][132] @0; Ah @0, Al @16384 (alias zl);
// red @33792 (512 thr * 8 B).
#define ARENA2_BYTES 37888
#define RED2_OFF     33792

// ---------------- weight pack: fragment-ordered -----------------------------
// hi: wP[mat*16384 + cb*2048 + kk*512 + l*8 + e]; lo at +98304.
// value = src[(kk*32 + (l>>4)*8 + e)*128 + cb*16 + (l&15)]
// mats: 0=ga 1=a 2=gb 3=b 4=go 5=o
__global__ void k_pack(const float* __restrict__ wga, const float* __restrict__ wa,
                       const float* __restrict__ wgb, const float* __restrict__ wb,
                       const float* __restrict__ wgo, const float* __restrict__ wo,
                       unsigned short* __restrict__ wP) {
  int gid = blockIdx.x * 256 + threadIdx.x;      // 6*16384 = 98304
  int mat = gid >> 14, idx = gid & 16383;
  int cb = idx >> 11;
  int kk = (idx >> 9) & 3;
  int l  = (idx >> 3) & 63;
  int e  = idx & 7;
  int col = cb * 16 + (l & 15);
  int k   = kk * 32 + (l >> 4) * 8 + e;
  const float* src = (mat == 0) ? wga : (mat == 1) ? wa : (mat == 2) ? wgb
                   : (mat == 3) ? wb  : (mat == 4) ? wgo : wo;
  float v = src[k * 128 + col];
  unsigned short h = f2b(v);
  wP[gid]         = h;
  wP[98304 + gid] = f2b(v - b2f(h));
}

// ---------------- fused-LN helpers (r18 verbatim) ---------------------------
// Parallel stats: each thread reads its row's GRP partials in ascending part
// order — identical values & FP order as a serial gather (bit-exact),
// computed redundantly by all threads of the row (deterministic).
template<int GRP>
__device__ __forceinline__ void ln_stats_lds(const float* red, int row,
                                             float& mean, float& rstd) {
  float S = 0.f, SS = 0.f;
#pragma unroll
  for (int p = 0; p < GRP; ++p) {
    S  += red[(row * GRP + p) * 2 + 0];
    SS += red[(row * GRP + p) * 2 + 1];
  }
  mean = S * (1.0f / 128.0f);
  const float var = SS * (1.0f / 128.0f) - mean * mean;
  rstd = rsqrtf(var + 1e-5f);
}

// 256-thread (k1) variant: row = t>>2, part = t&3, 32 cols/thread.
__device__ __forceinline__ void ln_sum(const f32x4 v[8], float* red, int t) {
  float s = 0.f, ss = 0.f;
#pragma unroll
  for (int j = 0; j < 8; ++j)
#pragma unroll
    for (int e = 0; e < 4; ++e) { float x = v[j][e]; s += x; ss += x * x; }
  red[t * 2 + 0] = s;
  red[t * 2 + 1] = ss;
}

__device__ __forceinline__ void ln_build(const f32x4 v[8],
                                         const f32x4* gp, const f32x4* bp,
                                         float mean, float rstd,
                                         char* Ah, char* Al, int row, int part) {
  const int swz = (row & 7) << 4;
#pragma unroll
  for (int cc = 0; cc < 4; ++cc) {
    u16x8 ph, pl;
#pragma unroll
    for (int e = 0; e < 8; ++e) {
      int j = cc * 2 + (e >> 2), ee = e & 3;
      float x = (v[j][ee] - mean) * rstd * gp[j][ee] + bp[j][ee];
      unsigned short h = f2b(x);
      ph[e] = h;
      pl[e] = f2b(x - b2f(h));
    }
    int off = ((part * 4 + cc) * 16) ^ swz;
    *(u16x8*)(Ah + row * 256 + off) = ph;
    *(u16x8*)(Al + row * 256 + off) = pl;
  }
}

// 512-thread (k2) variant: row = t>>3, part = t&7, 16 cols/thread.
__device__ __forceinline__ void ln_sum4(const f32x4 v[4], float* red, int t) {
  float s = 0.f, ss = 0.f;
#pragma unroll
  for (int j = 0; j < 4; ++j)
#pragma unroll
    for (int e = 0; e < 4; ++e) { float x = v[j][e]; s += x; ss += x * x; }
  red[t * 2 + 0] = s;
  red[t * 2 + 1] = ss;
}

__device__ __forceinline__ void ln_build4(const f32x4 v[4],
                                          const f32x4* gp, const f32x4* bp,
                                          float mean, float rstd,
                                          char* Ah, char* Al, int row, int part) {
  const int swz = (row & 7) << 4;
#pragma unroll
  for (int cc = 0; cc < 2; ++cc) {
    u16x8 ph, pl;
#pragma unroll
    for (int e = 0; e < 8; ++e) {
      int j = cc * 2 + (e >> 2), ee = e & 3;
      float x = (v[j][ee] - mean) * rstd * gp[j][ee] + bp[j][ee];
      unsigned short h = f2b(x);
      ph[e] = h;
      pl[e] = f2b(x - b2f(h));
    }
    int off = ((part * 2 + cc) * 16) ^ swz;
    *(u16x8*)(Ah + row * 256 + off) = ph;
    *(u16x8*)(Al + row * 256 + off) = pl;
  }
}

// ---------------- pass 1: MFMA (gb,b) + column-sum reduction ----------------
__global__ __launch_bounds__(256) void k1(
    const float* __restrict__ z,
    const float* __restrict__ lng, const float* __restrict__ lnb,
    const float* __restrict__ bgb, const float* __restrict__ bbv,
    const unsigned short* __restrict__ wT,
    float* __restrict__ partials)
{
  __shared__ __align__(16) char smem[ARENA1_BYTES];
  float* zl  = (float*)smem;                   // merge only (aliases Ah)
  char*  Ah  = smem;
  char*  Al  = smem + 16384;
  float* red = (float*)(smem + RED1_OFF);

  const int t = threadIdx.x;
  const int l = t & 63, wv = t >> 6;
  const int c15 = l & 15, kg = l >> 4;
  const int col0 = wv * 32 + c15;
  const int row = t >> 2, part = t & 3;        // LN mapping
  const int fl8 = l * 8;                        // fragment lane offset
  const int wv2 = wv * 2;

  const unsigned short* wgh = wT + 2 * 16384;            // gb hi (gate: hi only)
  const unsigned short* wlh = wT + 3 * 16384;            // b  hi
  const unsigned short* wll = wT + 98304 + 3 * 16384;    // b  lo
  const float vgb0 = bgb[col0], vgb1 = bgb[col0 + 16];
  const float vlb0 = bbv[col0], vlb1 = bbv[col0 + 16];
  const f32x4* gp = (const f32x4*)(lng + part * 32);
  const f32x4* bp = (const f32x4*)(lnb + part * 32);

  // loop-invariant kk=0/nt=0 weight frags, held in regs across all 8 iters
  const int bofs00 = (wv2 * 4) * 512 + fl8;
  const s16x8 Pg  = loadb(wgh + bofs00);
  const s16x8 Pbh = loadb(wlh + bofs00);
  const s16x8 Pbl = loadb(wll + bofs00);

  f32x4 breg[4][2];
#pragma unroll
  for (int mt = 0; mt < 4; ++mt)
#pragma unroll
    for (int nt = 0; nt < 2; ++nt) breg[mt][nt] = (f32x4)(0.0f);

  for (int it = 0; it < 8; ++it) {
    const long base = (long)(blockIdx.x * 8 + it) * 64;

    // ---- fused LN(z): global load -> red partials -> local stats -> tiles
    f32x4 v[8];
    {
      const float* zp = z + (base + row) * 128 + part * 32;
#pragma unroll
      for (int j = 0; j < 8; ++j) v[j] = ((const f32x4*)zp)[j];
      ln_sum(v, red, t);
    }
    __syncthreads();   // red visible; prev iter's tile reads complete
    float mean, rstd;
    ln_stats_lds<4>(red, row, mean, rstd);
    ln_build(v, gp, bp, mean, rstd, Ah, Al, row, part);
    __syncthreads();   // tiles visible; red reads done before next overwrite

    // ---- split GEMM (gb gate 1-term, b linear 3-term) ----
    f32x4 ag[4][2], al_[4][2];
#pragma unroll
    for (int mt = 0; mt < 4; ++mt)
#pragma unroll
      for (int nt = 0; nt < 2; ++nt) { ag[mt][nt] = (f32x4)(0.0f); al_[mt][nt] = (f32x4)(0.0f); }
#pragma unroll
    for (int kk = 0; kk < 4; ++kk) {
      s16x8 ah[4], alo[4];
#pragma unroll
      for (int mt = 0; mt < 4; ++mt) {
        int ar = mt * 16 + c15;
        int off = ar * 256 + ((kk * 64 + kg * 16) ^ ((ar & 7) << 4));
        ah[mt]  = __builtin_bit_cast(s16x8, *(const u16x8*)(Ah + off));
        alo[mt] = __builtin_bit_cast(s16x8, *(const u16x8*)(Al + off));
      }
#pragma unroll
      for (int nt = 0; nt < 2; ++nt) {
        int bofs = ((wv2 + nt) * 4 + kk) * 512 + fl8;
        s16x8 bgh, blh, bll;
        if (kk == 0 && nt == 0) { bgh = Pg; blh = Pbh; bll = Pbl; }
        else { bgh = loadb(wgh + bofs); blh = loadb(wlh + bofs); bll = loadb(wll + bofs); }
#pragma unroll
        for (int mt = 0; mt < 4; ++mt) {
          ag[mt][nt]  = MFMAB(ah[mt],  bgh, ag[mt][nt]);
          al_[mt][nt] = MFMAB(ah[mt],  blh, al_[mt][nt]);
          al_[mt][nt] = MFMAB(alo[mt], blh, al_[mt][nt]);
          al_[mt][nt] = MFMAB(ah[mt],  bll, al_[mt][nt]);
        }
      }
    }
#pragma unroll
    for (int nt = 0; nt < 2; ++nt) {
      float vg = nt ? vgb1 : vgb0, vl = nt ? vlb1 : vlb0;
#pragma unroll
      for (int mt = 0; mt < 4; ++mt)
#pragma unroll
        for (int r = 0; r < 4; ++r)
          breg[mt][nt][r] += sigm(ag[mt][nt][r] + vg) * (al_[mt][nt][r] + vl);
    }
  }

  __syncthreads();   // all tile reads done; arena reusable as f32 merge buf
  float* sm = zl;
#pragma unroll
  for (int mt = 0; mt < 2; ++mt)
#pragma unroll
    for (int nt = 0; nt < 2; ++nt) {
      int col = col0 + nt * 16;
#pragma unroll
      for (int r = 0; r < 4; ++r) {
        int krow = mt * 16 + kg * 4 + r;
        sm[krow * 128 + col] = breg[mt][nt][r] + breg[mt + 2][nt][r];
      }
    }
  __syncthreads();
  for (int i = 0; i < 16; ++i) {
    int e = i * 256 + t;
    partials[(long)blockIdx.x * 4096 + e] = sm[e];
  }
}

// ---------------- reductions (r5 verbatim) ----------------------------------
__global__ void k_red_a(const float* __restrict__ pin, double* __restrict__ pout) {
  int gid = blockIdx.x * 256 + threadIdx.x;
  int e = gid & 4095, chunk = gid >> 12;
  const float* p = pin + (long)chunk * 16 * 4096 + e;
  double a0 = 0, a1 = 0, a2 = 0, a3 = 0;
#pragma unroll
  for (int i = 0; i < 16; i += 4) {
    a0 += (double)p[(i + 0) * 4096]; a1 += (double)p[(i + 1) * 4096];
    a2 += (double)p[(i + 2) * 4096]; a3 += (double)p[(i + 3) * 4096];
  }
  pout[gid] = (a0 + a1) + (a2 + a3);
}

__global__ void k_red_b(const double* __restrict__ pin, float* __restrict__ sfin) {
  int e = blockIdx.x * 256 + threadIdx.x;
  double a0 = 0, a1 = 0, a2 = 0, a3 = 0;
#pragma unroll
  for (int i = 0; i < 64; i += 4) {
    a0 += pin[(i + 0) * 4096 + e]; a1 += pin[(i + 1) * 4096 + e];
    a2 += pin[(i + 2) * 4096 + e]; a3 += pin[(i + 3) * 4096 + e];
  }
  sfin[e] = (float)((a0 + a1) + (a2 + a3));
}

// ---------------- pass 2: 512 threads, 8 waves, 64x16 slice per wave --------
__global__ __launch_bounds__(512, 4) void k2(
    const float* __restrict__ z,
    const float* __restrict__ lnig, const float* __restrict__ lnib,
    const float* __restrict__ bga, const float* __restrict__ ba,
    const float* __restrict__ bgo,
    const float* __restrict__ lnog, const float* __restrict__ lnob,
    const float* __restrict__ bo,
    const unsigned short* __restrict__ wT,
    const float* __restrict__ sfin,
    float* __restrict__ out)
{
  __shared__ __align__(16) char smem[ARENA2_BYTES];
  float* zl  = (float*)smem;
  char*  Ah  = smem;
  char*  Al  = smem + 16384;
  float* red = (float*)(smem + RED2_OFF);

  const int t = threadIdx.x;
  const int l = t & 63, w = t >> 6;            // wave id in [0,8)
  const int c15 = l & 15, kg = l >> 4;
  const int col0 = w * 16 + c15;               // wave w owns cols [w*16, w*16+16)
  const int row = t >> 3, part = t & 7;        // LN mapping (16 cols/thread)
  const int fl8 = l * 8;
  const long base = (long)blockIdx.x * 64;

  const unsigned short* wgah = wT + 0 * 16384;           // ga hi
  const unsigned short* wah  = wT + 1 * 16384;           // a  hi
  const unsigned short* wal  = wT + 98304 + 1 * 16384;   // a  lo
  const unsigned short* wgoh = wT + 4 * 16384;           // go hi
  const unsigned short* woh  = wT + 5 * 16384;           // o  hi
  const unsigned short* wol  = wT + 98304 + 5 * 16384;   // o  lo
  const int bofs0 = (w * 4) * 512 + fl8;

  // prefetch kk=0 frags for phase 2+3 (drained by B1's vmcnt)
  const s16x8 pf_g  = loadb(wgah + bofs0);
  const s16x8 pf_ah = loadb(wah + bofs0);
  const s16x8 pf_al = loadb(wal + bofs0);
  const s16x8 pf_o  = loadb(wgoh + bofs0);

  // ---- phase 1: fused LN(z) -> tiles ----
  {
    f32x4 v[4];
    const float* zp = z + (base + row) * 128 + part * 16;
#pragma unroll
    for (int j = 0; j < 4; ++j) v[j] = ((const f32x4*)zp)[j];
    ln_sum4(v, red, t);
    __syncthreads();   // B1a: red visible
    float mean, rstd;
    ln_stats_lds<8>(red, row, mean, rstd);
    ln_build4(v, (const f32x4*)(lnig + part * 16), (const f32x4*)(lnib + part * 16),
              mean, rstd, Ah, Al, row, part);
  }
  __syncthreads();   // B1: tiles visible

  // ---- phase 2+3 FUSED: ga (gate 1-term), a (linear 3-term), go (1-term) --
  f32x4 ag[4], gg[4];
  {
    f32x4 g_[4], a_[4];
#pragma unroll
    for (int mt = 0; mt < 4; ++mt) {
      g_[mt] = (f32x4)(0.0f); a_[mt] = (f32x4)(0.0f); gg[mt] = (f32x4)(0.0f);
    }
#pragma unroll
    for (int kk = 0; kk < 4; ++kk) {
      s16x8 ah[4], alo[4];
#pragma unroll
      for (int mt = 0; mt < 4; ++mt) {
        int ar = mt * 16 + c15;
        int off = ar * 256 + ((kk * 64 + kg * 16) ^ ((ar & 7) << 4));
        ah[mt]  = __builtin_bit_cast(s16x8, *(const u16x8*)(Ah + off));
        alo[mt] = __builtin_bit_cast(s16x8, *(const u16x8*)(Al + off));
      }
      s16x8 g_h, a_h, a_l, o_h;
      if (kk == 0) { g_h = pf_g; a_h = pf_ah; a_l = pf_al; o_h = pf_o; }
      else {
        int bofs = (w * 4 + kk) * 512 + fl8;
        g_h = loadb(wgah + bofs);
        a_h = loadb(wah + bofs);
        a_l = loadb(wal + bofs);
        o_h = loadb(wgoh + bofs);
      }
#pragma unroll
      for (int mt = 0; mt < 4; ++mt) {
        g_[mt] = MFMAB(ah[mt],  g_h, g_[mt]);
        a_[mt] = MFMAB(ah[mt],  a_h, a_[mt]);
        a_[mt] = MFMAB(alo[mt], a_h, a_[mt]);
        a_[mt] = MFMAB(ah[mt],  a_l, a_[mt]);
        gg[mt] = MFMAB(ah[mt],  o_h, gg[mt]);
      }
    }
    float vga = bga[col0], vba = ba[col0], vgo = bgo[col0];
#pragma unroll
    for (int mt = 0; mt < 4; ++mt)
#pragma unroll
      for (int r = 0; r < 4; ++r) {
        ag[mt][r] = sigm(g_[mt][r] + vga) * (a_[mt][r] + vba);
        gg[mt][r] = sigm(gg[mt][r] + vgo);
      }
  }
  __syncthreads();   // B2: all tile reads done; arena reusable as f32 zl

  // prefetch kk=0 frags for phase 6 (held across phases 4-5)
  const s16x8 pf_wh = loadb(woh + bofs0);
  const s16x8 pf_wl = loadb(wol + bofs0);

  // ---- phase 4: kv = a * s[k] -> zl ----
#pragma unroll
  for (int mt = 0; mt < 4; ++mt)
#pragma unroll
    for (int r = 0; r < 4; ++r) {
      int rw = mt * 16 + kg * 4 + r;
      zl[rw * ZL_STRIDE + col0] = ag[mt][r] * sfin[(rw & 31) * 128 + col0];
    }
  __syncthreads();   // B3: kv visible

  // ---- phase 5: fused LN(kv) -> tiles ----
  {
    f32x4 v[4];
    const f32x4* kp = (const f32x4*)(zl + row * ZL_STRIDE + part * 16);
#pragma unroll
    for (int j = 0; j < 4; ++j) v[j] = kp[j];
    ln_sum4(v, red, t);
    __syncthreads();   // B4a: red visible AND all kv (zl) reads complete
    float mean, rstd;
    ln_stats_lds<8>(red, row, mean, rstd);
    // build writes Ah/Al (alias zl) — safe: no zl reads after B4a; red is
    // a disjoint region so concurrent red reads don't alias these writes.
    ln_build4(v, (const f32x4*)(lnog + part * 16), (const f32x4*)(lnob + part * 16),
              mean, rstd, Ah, Al, row, part);
  }
  __syncthreads();   // B5: tiles visible

  // ---- phase 6: w_o GEMM (full 3-term) ----
  f32x4 acc[4];
#pragma unroll
  for (int mt = 0; mt < 4; ++mt) acc[mt] = (f32x4)(0.0f);
  {
#pragma unroll
    for (int kk = 0; kk < 4; ++kk) {
      s16x8 ah[4], alo[4];
#pragma unroll
      for (int mt = 0; mt < 4; ++mt) {
        int ar = mt * 16 + c15;
        int off = ar * 256 + ((kk * 64 + kg * 16) ^ ((ar & 7) << 4));
        ah[mt]  = __builtin_bit_cast(s16x8, *(const u16x8*)(Ah + off));
        alo[mt] = __builtin_bit_cast(s16x8, *(const u16x8*)(Al + off));
      }
      s16x8 o_h, o_l;
      if (kk == 0) { o_h = pf_wh; o_l = pf_wl; }
      else {
        int bofs = (w * 4 + kk) * 512 + fl8;
        o_h = loadb(woh + bofs);
        o_l = loadb(wol + bofs);
      }
#pragma unroll
      for (int mt = 0; mt < 4; ++mt) {
        acc[mt] = MFMAB(ah[mt],  o_h, acc[mt]);
        acc[mt] = MFMAB(alo[mt], o_h, acc[mt]);
        acc[mt] = MFMAB(ah[mt],  o_l, acc[mt]);
      }
    }
  }

  // ---- phase 7: out = sigm(go) * (acc + b_o) ----
  {
    float bov = bo[col0];
#pragma unroll
    for (int mt = 0; mt < 4; ++mt)
#pragma unroll
      for (int r = 0; r < 4; ++r) {
        int rw = mt * 16 + kg * 4 + r;
        out[(base + rw) * 128 + col0] = gg[mt][r] * (acc[mt][r] + bov);
      }
  }
}

// ---------------------------------------------------------------------------
extern "C" void kernel_launch(void* const* d_in, const int* in_sizes, int n_in,
                              void* d_out, int out_size, void* d_ws, size_t ws_size,
                              hipStream_t stream) {
  const float* z    = (const float*)d_in[0];
  const float* lnig = (const float*)d_in[1];
  const float* lnib = (const float*)d_in[2];
  const float* w_a  = (const float*)d_in[3];
  const float* b_a  = (const float*)d_in[4];
  const float* w_ga = (const float*)d_in[5];
  const float* b_ga = (const float*)d_in[6];
  const float* w_b  = (const float*)d_in[7];
  const float* b_b  = (const float*)d_in[8];
  const float* w_gb = (const float*)d_in[9];
  const float* b_gb = (const float*)d_in[10];
  const float* lnog = (const float*)d_in[11];
  const float* lnob = (const float*)d_in[12];
  const float* w_go = (const float*)d_in[13];
  const float* b_go = (const float*)d_in[14];
  const float* w_o  = (const float*)d_in[15];
  const float* b_o  = (const float*)d_in[16];

  // ws: sfin 16KB @0, wP 384KB @16384
  float* sfin = (float*)d_ws;
  unsigned short* wT = (unsigned short*)((char*)d_ws + 16384);

  // big scratch in d_out (fully overwritten by k2):
  float*  partials  = (float*)d_out;                        // 16 MB
  double* partials2 = (double*)((char*)d_out + 16777216);   //  2 MB

  k_pack<<<384, 256, 0, stream>>>(w_ga, w_a, w_gb, w_b, w_go, w_o, wT);
  k1<<<1024, 256, 0, stream>>>(z, lnig, lnib, b_gb, b_b, wT, partials);
  k_red_a<<<1024, 256, 0, stream>>>(partials, partials2);
  k_red_b<<<16, 256, 0, stream>>>(partials2, sfin);
  k2<<<8192, 512, 0, stream>>>(z, lnig, lnib,
                               b_ga, b_a, b_go, lnog, lnob, b_o,
                               wT, sfin, (float*)d_out);
}